// Round 1
// baseline (1191.339 us; speedup 1.0000x reference)
//
#include <hip/hip_runtime.h>
#include <hip/hip_bf16.h>

// ---------- types ----------
typedef __attribute__((ext_vector_type(8))) __bf16 bf16x8;
typedef __attribute__((ext_vector_type(8))) short  short8;
typedef __attribute__((ext_vector_type(4))) float  f32x4;
typedef unsigned short u16;
typedef unsigned int   u32;

__device__ __forceinline__ u16 f2bf(float f) {
  u32 u = __builtin_bit_cast(u32, f);
  u += 0x7fffu + ((u >> 16) & 1u);          // round-to-nearest-even
  return (u16)(u >> 16);
}
__device__ __forceinline__ float bf2f(u16 h) {
  return __builtin_bit_cast(float, (u32)h << 16);
}

#define MFMA_BF16(a, b, c) __builtin_amdgcn_mfma_f32_16x16x32_bf16( \
    __builtin_bit_cast(bf16x8, (a)), __builtin_bit_cast(bf16x8, (b)), (c), 0, 0, 0)

__device__ __forceinline__ void gload_lds16(const void* g, void* l) {
  __builtin_amdgcn_global_load_lds(
      (const __attribute__((address_space(1))) void*)g,
      (__attribute__((address_space(3))) void*)l, 16, 0, 0);
}

// ---------- problem constants ----------
// b=2, s=2048, d=2048, h=16, hd=128
#define SEQ   2048
#define DMODEL 2048
#define NH    16
#define HD    128

// ---------- workspace layout (bytes) ----------
static constexpr size_t SZ_MAT   = 4096ull * 2048 * 2;        // (b*s, d) bf16 = 16 MiB
static constexpr size_t OFF_XB   = 0;
static constexpr size_t OFF_WQKVT= OFF_XB   + SZ_MAT;          // Wq^T|Wk^T|Wv^T  (3*2048*2048 bf16)
static constexpr size_t OFF_WOT  = OFF_WQKVT+ 3ull*2048*2048*2;
static constexpr size_t OFF_Q    = OFF_WOT  + 2048ull*2048*2;
static constexpr size_t OFF_K    = OFF_Q    + SZ_MAT;
static constexpr size_t OFF_VT   = OFF_K    + SZ_MAT;          // Vt[b*2048 + h*128 + dd][s]
static constexpr size_t OFF_CTX  = OFF_VT   + SZ_MAT;
static constexpr size_t OFF_COS  = OFF_CTX  + SZ_MAT;
static constexpr size_t OFF_SIN  = OFF_COS  + 2048ull*64*4;
static constexpr size_t WS_NEED  = OFF_SIN  + 2048ull*64*4;    // ~113 MiB

// ---------- prep kernels ----------
__global__ void cast_x_kernel(const float* __restrict__ x, u16* __restrict__ xb, int n4) {
  int id = blockIdx.x * blockDim.x + threadIdx.x;
  if (id >= n4) return;
  float4 v = ((const float4*)x)[id];
  ushort4 o;
  o.x = f2bf(v.x); o.y = f2bf(v.y); o.z = f2bf(v.z); o.w = f2bf(v.w);
  ((ushort4*)xb)[id] = o;
}

// cast fp32 W[k][n] -> bf16 W^T[n][k]; z selects which weight
__global__ void castT_w_kernel(const float* __restrict__ W0, const float* __restrict__ W1,
                               const float* __restrict__ W2, const float* __restrict__ W3,
                               u16* __restrict__ Wqkvt, u16* __restrict__ Wot) {
  __shared__ float tile[32][33];
  int z = blockIdx.z;
  const float* W = (z == 0) ? W0 : (z == 1) ? W1 : (z == 2) ? W2 : W3;
  u16* Out = (z < 3) ? (Wqkvt + (size_t)z * 2048 * 2048) : Wot;
  int n0 = blockIdx.x * 32, k0 = blockIdx.y * 32;
  int tx = threadIdx.x, ty = threadIdx.y;   // (32,8)
  #pragma unroll
  for (int i = 0; i < 4; i++)
    tile[ty + 8 * i][tx] = W[(size_t)(k0 + ty + 8 * i) * 2048 + n0 + tx];
  __syncthreads();
  #pragma unroll
  for (int i = 0; i < 4; i++)
    Out[(size_t)(n0 + ty + 8 * i) * 2048 + k0 + tx] = f2bf(tile[tx][ty + 8 * i]);
}

__global__ void rope_table_kernel(float* __restrict__ ct, float* __restrict__ st) {
  int id = blockIdx.x * blockDim.x + threadIdx.x;  // 2048*64
  int pos = id >> 6, j = id & 63;
  // inv_freq = 10000^(-j/64) = 2^(-j*log2(10000)/64)
  float inv = exp2f(-(float)j * (13.287712379549449f / 64.0f));
  float a = (float)pos * inv;
  ct[id] = cosf(a);
  st[id] = sinf(a);
}

// in-place RoPE on (4096, 2048) bf16, col = h*128 + dd ; grid.y: 0=Q 1=K
__global__ void rope_apply_kernel(u16* __restrict__ Q, u16* __restrict__ K,
                                  const float* __restrict__ ct, const float* __restrict__ st) {
  int id = blockIdx.x * blockDim.x + threadIdx.x;    // < 4096*16*64
  u16* P = blockIdx.y ? K : Q;
  int row = id >> 10;
  int r = id & 1023;
  int hh = r >> 6, j = r & 63;
  int pos = row & 2047;
  size_t base = (size_t)row * 2048 + hh * 128 + j;
  float x1 = bf2f(P[base]), x2 = bf2f(P[base + 64]);
  float c = ct[pos * 64 + j], s = st[pos * 64 + j];
  P[base]      = f2bf(x1 * c - x2 * s);
  P[base + 64] = f2bf(x2 * c + x1 * s);
}

// ---------- GEMM: C[M x N] = A[M x K](bf16,row) @ Bt[N x K]^T (bf16,row) ----------
// 128x128 tile, BK=32, 4 waves (2x2), each wave 64x64 = 4x4 frags of 16x16x32 MFMA.
// EPI 0: N=6144 fused QKV epilogue (Q,K row-major bf16; V transposed per head).
// EPI 1: fp32 C, N=2048.
template <int EPI>
__global__ __launch_bounds__(256)
void gemm_bt_kernel(const u16* __restrict__ A, const u16* __restrict__ Bt,
                    u16* __restrict__ Qo, u16* __restrict__ Ko, u16* __restrict__ Vto,
                    float* __restrict__ Co, int K) {
  __shared__ u16 Al[128 * 32];
  __shared__ u16 Bl[128 * 32];
  const int tid = threadIdx.x;
  const int lane = tid & 63;
  const int w = tid >> 6;
  const int grp = lane >> 4, lr = lane & 15;
  const int bm = blockIdx.y, bn = blockIdx.x;
  const int wm = w >> 1, wn = w & 1;
  f32x4 acc[4][4] = {};
  const char* Ab = (const char*)(A + (size_t)bm * 128 * K);
  const char* Bb = (const char*)(Bt + (size_t)bn * 128 * K);
  const int c0 = tid, c1 = tid + 256;              // 16B chunks of the 8KB tile
  const int rA0 = c0 >> 2, cb0 = (c0 & 3) * 16;
  const int rA1 = c1 >> 2, cb1 = (c1 & 3) * 16;

  for (int kt = 0; kt < K; kt += 32) {
    gload_lds16(Ab + (size_t)rA0 * K * 2 + kt * 2 + cb0, (char*)Al + c0 * 16);
    gload_lds16(Ab + (size_t)rA1 * K * 2 + kt * 2 + cb1, (char*)Al + c1 * 16);
    gload_lds16(Bb + (size_t)rA0 * K * 2 + kt * 2 + cb0, (char*)Bl + c0 * 16);
    gload_lds16(Bb + (size_t)rA1 * K * 2 + kt * 2 + cb1, (char*)Bl + c1 * 16);
    __syncthreads();   // compiler drains vmcnt before s_barrier
    short8 af[4], bf[4];
    #pragma unroll
    for (int mi = 0; mi < 4; mi++)
      af[mi] = *(const short8*)(Al + (wm * 64 + mi * 16 + lr) * 32 + grp * 8);
    #pragma unroll
    for (int nj = 0; nj < 4; nj++)
      bf[nj] = *(const short8*)(Bl + (wn * 64 + nj * 16 + lr) * 32 + grp * 8);
    #pragma unroll
    for (int mi = 0; mi < 4; mi++)
      #pragma unroll
      for (int nj = 0; nj < 4; nj++)
        acc[mi][nj] = MFMA_BF16(af[mi], bf[nj], acc[mi][nj]);
    __syncthreads();
  }

  // epilogue: C/D layout col = lane&15, row = 4*(lane>>4)+reg  [verified m89/m91]
  const int rowBase = bm * 128 + wm * 64 + grp * 4;
  if (EPI == 0) {
    const int seg = bn >> 4;                       // 0=Q 1=K 2=V (2048-col segments)
    const int colBase = (bn & 15) * 128 + wn * 64 + lr;
    if (seg < 2) {
      u16* O = seg ? Ko : Qo;
      #pragma unroll
      for (int mi = 0; mi < 4; mi++)
        #pragma unroll
        for (int nj = 0; nj < 4; nj++) {
          int col = colBase + nj * 16;
          int row = rowBase + mi * 16;
          #pragma unroll
          for (int r = 0; r < 4; r++)
            O[(size_t)(row + r) * 2048 + col] = f2bf(acc[mi][nj][r]);
        }
    } else {
      // V: write transposed Vt[(b*2048 + h*128+dd)][s]; the 4 regs are consecutive s
      #pragma unroll
      for (int mi = 0; mi < 4; mi++) {
        int row = rowBase + mi * 16;               // = b*2048 + s
        int b = row >> 11, s = row & 2047;
        #pragma unroll
        for (int nj = 0; nj < 4; nj++) {
          int colv = colBase + nj * 16;            // h*128 + dd
          ushort4 o;
          o.x = f2bf(acc[mi][nj][0]); o.y = f2bf(acc[mi][nj][1]);
          o.z = f2bf(acc[mi][nj][2]); o.w = f2bf(acc[mi][nj][3]);
          *(ushort4*)(Vto + (size_t)(b * 2048 + colv) * 2048 + s) = o;
        }
      }
    }
  } else {
    const int colBase = bn * 128 + wn * 64 + lr;
    #pragma unroll
    for (int mi = 0; mi < 4; mi++)
      #pragma unroll
      for (int nj = 0; nj < 4; nj++)
        #pragma unroll
        for (int r = 0; r < 4; r++)
          Co[(size_t)(rowBase + mi * 16 + r) * 2048 + colBase + nj * 16] = acc[mi][nj][r];
  }
}

// ---------- flash attention (causal), swapped-QK^T, in-register softmax ----------
// grid (32 qtiles, 32 bh), 256 thr = 4 waves, wave w owns q rows qt*64+w*16 .. +16.
__global__ __launch_bounds__(256)
void attn_kernel(const u16* __restrict__ Q, const u16* __restrict__ K,
                 const u16* __restrict__ Vt, u16* __restrict__ ctx) {
  const int qt = blockIdx.x, bh = blockIdx.y;
  const int b = bh >> 4, h = bh & 15;
  const int w = threadIdx.x >> 6, lane = threadIdx.x & 63;
  const int grp = lane >> 4, lr = lane & 15;
  const int q0 = qt * 64 + w * 16;
  const int qrow = q0 + lr;                       // lane's q row (B-operand n = lane&15)
  const u16* Qp = Q + ((size_t)(b * 2048 + qrow)) * 2048 + h * 128;
  short8 qf[4];
  #pragma unroll
  for (int kk = 0; kk < 4; kk++)
    qf[kk] = *(const short8*)(Qp + kk * 32 + grp * 8);

  f32x4 acc_o[8] = {};                            // O^T[dd][q]: 8 dd-frags
  float m_run = -3.0e38f, l_run = 0.0f;
  const float ce = 0.08838834764831845f * 1.4426950408889634f; // 1/sqrt(128) * log2(e)
  const u16* Kb = K + ((size_t)b * 2048) * 2048 + h * 128;
  const u16* Vb = Vt + ((size_t)(b * 2048 + h * 128)) * 2048;

  for (int kvt = 0; kvt <= qt; kvt++) {
    const int kv0 = kvt * 64;
    // S^T[kv][q] = mfma(K-rows, Q-rows) over d=128
    f32x4 sa[4] = {};
    #pragma unroll
    for (int kk = 0; kk < 4; kk++) {
      #pragma unroll
      for (int mi = 0; mi < 4; mi++) {
        short8 kf = *(const short8*)(Kb + (size_t)(kv0 + mi * 16 + lr) * 2048 + kk * 32 + grp * 8);
        sa[mi] = MFMA_BF16(kf, qf[kk], sa[mi]);
      }
    }
    // mask + online softmax; lane holds 16 scores of ONE q-row (kv = kv0+16*mi+4*grp+r)
    float p[4][4];
    float tmax = -3.0e38f;
    const bool diag = (kvt == qt);
    #pragma unroll
    for (int mi = 0; mi < 4; mi++) {
      #pragma unroll
      for (int r = 0; r < 4; r++) {
        float s = sa[mi][r];
        if (diag) {
          int kv = kv0 + mi * 16 + grp * 4 + r;
          if (kv > qrow) s = -3.0e38f;
        }
        p[mi][r] = s;
        tmax = fmaxf(tmax, s);
      }
    }
    tmax = fmaxf(tmax, __shfl_xor(tmax, 16, 64));
    tmax = fmaxf(tmax, __shfl_xor(tmax, 32, 64));
    const float m_new = fmaxf(m_run, tmax);
    const float alpha = exp2f((m_run - m_new) * ce);
    float psum = 0.0f;
    #pragma unroll
    for (int mi = 0; mi < 4; mi++)
      #pragma unroll
      for (int r = 0; r < 4; r++) {
        float e = exp2f((p[mi][r] - m_new) * ce);
        p[mi][r] = e;
        psum += e;
      }
    psum += __shfl_xor(psum, 16, 64);
    psum += __shfl_xor(psum, 32, 64);
    l_run = l_run * alpha + psum;
    m_run = m_new;
    #pragma unroll
    for (int mi = 0; mi < 8; mi++) acc_o[mi] *= alpha;

    // P^T accumulator regs feed PV's B-operand directly (split-k mapping)
    short8 pb[2];
    #pragma unroll
    for (int kb = 0; kb < 2; kb++) {
      short8 t;
      #pragma unroll
      for (int i = 0; i < 4; i++) {
        t[i]     = (short)f2bf(p[2 * kb][i]);
        t[4 + i] = (short)f2bf(p[2 * kb + 1][i]);
      }
      pb[kb] = t;
    }
    // O^T[dd][q] += Vt-rows (A, m=dd) x P^T (B); A loaded with same split-k mapping:
    // elem i at kv = kv0 + kb*32 + 4*grp + (i&3) + 16*(i>>2)  -> two 8B loads
    #pragma unroll
    for (int mi = 0; mi < 8; mi++) {
      #pragma unroll
      for (int kb = 0; kb < 2; kb++) {
        const u16* vp = Vb + (size_t)(mi * 16 + lr) * 2048 + kv0 + kb * 32 + grp * 4;
        union { short8 v; uint2 hh[2]; } uv;
        uv.hh[0] = *(const uint2*)vp;
        uv.hh[1] = *(const uint2*)(vp + 16);
        acc_o[mi] = MFMA_BF16(uv.v, pb[kb], acc_o[mi]);
      }
    }
  }

  const float inv_l = 1.0f / l_run;
  u16* Cp = ctx + ((size_t)(b * 2048 + qrow)) * 2048 + h * 128;
  #pragma unroll
  for (int mi = 0; mi < 8; mi++) {
    ushort4 o;
    o.x = f2bf(acc_o[mi][0] * inv_l);
    o.y = f2bf(acc_o[mi][1] * inv_l);
    o.z = f2bf(acc_o[mi][2] * inv_l);
    o.w = f2bf(acc_o[mi][3] * inv_l);
    *(ushort4*)(Cp + mi * 16 + grp * 4) = o;
  }
}

// ---------- launch ----------
extern "C" void kernel_launch(void* const* d_in, const int* in_sizes, int n_in,
                              void* d_out, int out_size, void* d_ws, size_t ws_size,
                              hipStream_t stream) {
  const float* x  = (const float*)d_in[0];
  const float* Wq = (const float*)d_in[1];
  const float* Wk = (const float*)d_in[2];
  const float* Wv = (const float*)d_in[3];
  const float* Wo = (const float*)d_in[4];
  float* out = (float*)d_out;
  char* ws = (char*)d_ws;
  if (ws_size < WS_NEED) return;   // clean failure instead of OOB

  u16* xb    = (u16*)(ws + OFF_XB);
  u16* Wqkvt = (u16*)(ws + OFF_WQKVT);
  u16* Wot   = (u16*)(ws + OFF_WOT);
  u16* Qb    = (u16*)(ws + OFF_Q);
  u16* Kb    = (u16*)(ws + OFF_K);
  u16* Vtb   = (u16*)(ws + OFF_VT);
  u16* ctxb  = (u16*)(ws + OFF_CTX);
  float* ctab = (float*)(ws + OFF_COS);
  float* stab = (float*)(ws + OFF_SIN);

  cast_x_kernel<<<8192, 256, 0, stream>>>(x, xb, 2097152);
  castT_w_kernel<<<dim3(64, 64, 4), dim3(32, 8), 0, stream>>>(Wq, Wk, Wv, Wo, Wqkvt, Wot);
  rope_table_kernel<<<512, 256, 0, stream>>>(ctab, stab);
  gemm_bt_kernel<0><<<dim3(48, 32), 256, 0, stream>>>(xb, Wqkvt, Qb, Kb, Vtb, nullptr, 2048);
  rope_apply_kernel<<<dim3(16384, 2), 256, 0, stream>>>(Qb, Kb, ctab, stab);
  attn_kernel<<<dim3(32, 32), 256, 0, stream>>>(Qb, Kb, Vtb, ctxb);
  gemm_bt_kernel<1><<<dim3(16, 32), 256, 0, stream>>>(ctxb, Wot, nullptr, nullptr, nullptr, out, 2048);
}

// Round 3
// 463.851 us; speedup vs baseline: 2.5684x; 2.5684x over previous
//
#include <hip/hip_runtime.h>
#include <hip/hip_bf16.h>

// ---------- types ----------
typedef __attribute__((ext_vector_type(8))) __bf16 bf16x8;
typedef __attribute__((ext_vector_type(8))) short  short8;
typedef __attribute__((ext_vector_type(4))) float  f32x4;
typedef unsigned short u16;
typedef unsigned int   u32;

__device__ __forceinline__ u16 f2bf(float f) {
  u32 u = __builtin_bit_cast(u32, f);
  u += 0x7fffu + ((u >> 16) & 1u);          // round-to-nearest-even
  return (u16)(u >> 16);
}
__device__ __forceinline__ float bf2f(u16 h) {
  return __builtin_bit_cast(float, (u32)h << 16);
}

#define MFMA_BF16(a, b, c) __builtin_amdgcn_mfma_f32_16x16x32_bf16( \
    __builtin_bit_cast(bf16x8, (a)), __builtin_bit_cast(bf16x8, (b)), (c), 0, 0, 0)

__device__ __forceinline__ void gload_lds16(const void* g, void* l) {
  __builtin_amdgcn_global_load_lds(
      (const __attribute__((address_space(1))) void*)g,
      (__attribute__((address_space(3))) void*)l, 16, 0, 0);
}

// ---------- problem constants ----------
// b=2, s=2048, d=2048, h=16, hd=128
#define SEQ   2048
#define DMODEL 2048
#define NH    16
#define HD    128

// ---------- workspace layout (bytes) ----------
static constexpr size_t SZ_MAT   = 4096ull * 2048 * 2;        // (b*s, d) bf16 = 16 MiB
static constexpr size_t OFF_XB   = 0;
static constexpr size_t OFF_WQKVT= OFF_XB   + SZ_MAT;          // Wq^T|Wk^T|Wv^T
static constexpr size_t OFF_WOT  = OFF_WQKVT+ 3ull*2048*2048*2;
static constexpr size_t OFF_Q    = OFF_WOT  + 2048ull*2048*2;
static constexpr size_t OFF_K    = OFF_Q    + SZ_MAT;
static constexpr size_t OFF_VT   = OFF_K    + SZ_MAT;          // Vp[b*2048+h*128+dd][s_perm]
static constexpr size_t OFF_CTX  = OFF_VT   + SZ_MAT;
static constexpr size_t OFF_COS  = OFF_CTX  + SZ_MAT;
static constexpr size_t OFF_SIN  = OFF_COS  + 2048ull*64*4;
static constexpr size_t WS_NEED  = OFF_SIN  + 2048ull*64*4;    // ~113 MiB

// ---------- prep kernels ----------
__global__ void cast_x_kernel(const float* __restrict__ x, u16* __restrict__ xb, int n4) {
  int id = blockIdx.x * blockDim.x + threadIdx.x;
  if (id >= n4) return;
  float4 v = ((const float4*)x)[id];
  ushort4 o;
  o.x = f2bf(v.x); o.y = f2bf(v.y); o.z = f2bf(v.z); o.w = f2bf(v.w);
  ((ushort4*)xb)[id] = o;
}

// cast fp32 W[k][n] -> bf16 W^T[n][k]; z selects which weight
__global__ void castT_w_kernel(const float* __restrict__ W0, const float* __restrict__ W1,
                               const float* __restrict__ W2, const float* __restrict__ W3,
                               u16* __restrict__ Wqkvt, u16* __restrict__ Wot) {
  __shared__ float tile[32][33];
  int z = blockIdx.z;
  const float* W = (z == 0) ? W0 : (z == 1) ? W1 : (z == 2) ? W2 : W3;
  u16* Out = (z < 3) ? (Wqkvt + (size_t)z * 2048 * 2048) : Wot;
  int n0 = blockIdx.x * 32, k0 = blockIdx.y * 32;
  int tx = threadIdx.x, ty = threadIdx.y;   // (32,8)
  #pragma unroll
  for (int i = 0; i < 4; i++)
    tile[ty + 8 * i][tx] = W[(size_t)(k0 + ty + 8 * i) * 2048 + n0 + tx];
  __syncthreads();
  #pragma unroll
  for (int i = 0; i < 4; i++)
    Out[(size_t)(n0 + ty + 8 * i) * 2048 + k0 + tx] = f2bf(tile[tx][ty + 8 * i]);
}

__global__ void rope_table_kernel(float* __restrict__ ct, float* __restrict__ st) {
  int id = blockIdx.x * blockDim.x + threadIdx.x;  // 2048*64
  int pos = id >> 6, j = id & 63;
  float inv = exp2f(-(float)j * (13.287712379549449f / 64.0f));
  float a = (float)pos * inv;
  ct[id] = cosf(a);
  st[id] = sinf(a);
}

// in-place RoPE on (4096, 2048) bf16, col = h*128 + dd ; grid.y: 0=Q 1=K
__global__ void rope_apply_kernel(u16* __restrict__ Q, u16* __restrict__ K,
                                  const float* __restrict__ ct, const float* __restrict__ st) {
  int id = blockIdx.x * blockDim.x + threadIdx.x;    // < 4096*16*64
  u16* P = blockIdx.y ? K : Q;
  int row = id >> 10;
  int r = id & 1023;
  int hh = r >> 6, j = r & 63;
  int pos = row & 2047;
  size_t base = (size_t)row * 2048 + hh * 128 + j;
  float x1 = bf2f(P[base]), x2 = bf2f(P[base + 64]);
  float c = ct[pos * 64 + j], s = st[pos * 64 + j];
  P[base]      = f2bf(x1 * c - x2 * s);
  P[base + 64] = f2bf(x2 * c + x1 * s);
}

// ---------- GEMM: C[M x N] = A[M x K](bf16,row) @ Bt[N x K]^T (bf16,row) ----------
// 128x128 tile, BK=32, 4 waves (2x2). EPI 0: fused QKV epilogue (V written
// transposed AND kv-permuted for the attention PV split-k layout). EPI 1: fp32 C.
template <int EPI>
__global__ __launch_bounds__(256)
void gemm_bt_kernel(const u16* __restrict__ A, const u16* __restrict__ Bt,
                    u16* __restrict__ Qo, u16* __restrict__ Ko, u16* __restrict__ Vto,
                    float* __restrict__ Co, int K) {
  __shared__ u16 Al[128 * 32];
  __shared__ u16 Bl[128 * 32];
  const int tid = threadIdx.x;
  const int lane = tid & 63;
  const int w = tid >> 6;
  const int grp = lane >> 4, lr = lane & 15;
  const int bm = blockIdx.y, bn = blockIdx.x;
  const int wm = w >> 1, wn = w & 1;
  f32x4 acc[4][4] = {};
  const char* Ab = (const char*)(A + (size_t)bm * 128 * K);
  const char* Bb = (const char*)(Bt + (size_t)bn * 128 * K);
  const int c0 = tid, c1 = tid + 256;              // 16B chunks of the 8KB tile
  const int rA0 = c0 >> 2, cb0 = (c0 & 3) * 16;
  const int rA1 = c1 >> 2, cb1 = (c1 & 3) * 16;

  for (int kt = 0; kt < K; kt += 32) {
    gload_lds16(Ab + (size_t)rA0 * K * 2 + kt * 2 + cb0, (char*)Al + c0 * 16);
    gload_lds16(Ab + (size_t)rA1 * K * 2 + kt * 2 + cb1, (char*)Al + c1 * 16);
    gload_lds16(Bb + (size_t)rA0 * K * 2 + kt * 2 + cb0, (char*)Bl + c0 * 16);
    gload_lds16(Bb + (size_t)rA1 * K * 2 + kt * 2 + cb1, (char*)Bl + c1 * 16);
    __syncthreads();   // compiler drains vmcnt before s_barrier
    short8 af[4], bf[4];
    #pragma unroll
    for (int mi = 0; mi < 4; mi++)
      af[mi] = *(const short8*)(Al + (wm * 64 + mi * 16 + lr) * 32 + grp * 8);
    #pragma unroll
    for (int nj = 0; nj < 4; nj++)
      bf[nj] = *(const short8*)(Bl + (wn * 64 + nj * 16 + lr) * 32 + grp * 8);
    #pragma unroll
    for (int mi = 0; mi < 4; mi++)
      #pragma unroll
      for (int nj = 0; nj < 4; nj++)
        acc[mi][nj] = MFMA_BF16(af[mi], bf[nj], acc[mi][nj]);
    __syncthreads();
  }

  // epilogue: C/D layout col = lane&15, row = 4*(lane>>4)+reg  [verified m89/m91]
  const int rowBase = bm * 128 + wm * 64 + grp * 4;
  if (EPI == 0) {
    const int seg = bn >> 4;                       // 0=Q 1=K 2=V (2048-col segments)
    const int colBase = (bn & 15) * 128 + wn * 64 + lr;
    if (seg < 2) {
      u16* O = seg ? Ko : Qo;
      #pragma unroll
      for (int mi = 0; mi < 4; mi++)
        #pragma unroll
        for (int nj = 0; nj < 4; nj++) {
          int col = colBase + nj * 16;
          int row = rowBase + mi * 16;
          #pragma unroll
          for (int r = 0; r < 4; r++)
            O[(size_t)(row + r) * 2048 + col] = f2bf(acc[mi][nj][r]);
        }
    } else {
      // V: write Vp[(b*2048 + h*128+dd)][s_perm]; regs are 4 consecutive s.
      // s_perm makes the attention PV A-fragment a contiguous ds_read_b128:
      // within each 32-block, pos = grp8*8 + hi*4 + r for s = grp8*4 + hi*16 + r.
      #pragma unroll
      for (int mi = 0; mi < 4; mi++) {
        int row = rowBase + mi * 16;               // = b*2048 + s (s multiple of 4)
        int b = row >> 11, s = row & 2047;
        int sp = (s & ~31) | (((s >> 2) & 3) << 3) | (((s >> 4) & 1) << 2);
        #pragma unroll
        for (int nj = 0; nj < 4; nj++) {
          int colv = colBase + nj * 16;            // h*128 + dd
          ushort4 o;
          o.x = f2bf(acc[mi][nj][0]); o.y = f2bf(acc[mi][nj][1]);
          o.z = f2bf(acc[mi][nj][2]); o.w = f2bf(acc[mi][nj][3]);
          *(ushort4*)(Vto + (size_t)(b * 2048 + colv) * 2048 + sp) = o;
        }
      }
    }
  } else {
    const int colBase = bn * 128 + wn * 64 + lr;
    #pragma unroll
    for (int mi = 0; mi < 4; mi++)
      #pragma unroll
      for (int nj = 0; nj < 4; nj++)
        #pragma unroll
        for (int r = 0; r < 4; r++)
          Co[(size_t)(rowBase + mi * 16 + r) * 2048 + colBase + nj * 16] = acc[mi][nj][r];
  }
}

// ---------- flash attention v2 (causal), LDS-staged K/V, double-buffered ----------
// grid (16 qtiles, 32 bh), 512 thr = 8 waves; wave w owns q rows qt*128+w*16..+16.
// K tile [64 kv][128 d] and V tile [128 dd][64 kv-permuted], both 16B-slot
// XOR-swizzled (slot ^= row&7) via pre-swizzled global source (rule #21).
__global__ __launch_bounds__(512, 4)
void attn_kernel(const u16* __restrict__ Q, const u16* __restrict__ K,
                 const u16* __restrict__ Vt, u16* __restrict__ ctx) {
  __shared__ u16 Kl[2][64 * 128];   // 16 KB each
  __shared__ u16 Vl[2][128 * 64];   // 16 KB each
  const int qt = blockIdx.x, bh = blockIdx.y;
  const int b = bh >> 4, h = bh & 15;
  const int tid = threadIdx.x;
  const int w = tid >> 6, lane = tid & 63;
  const int grp = lane >> 4, lr = lane & 15;
  const int q0w = qt * 128 + w * 16;
  const int qrow = q0w + lr;
  const u16* Qp = Q + ((size_t)(b * 2048 + qrow)) * 2048 + h * 128;
  short8 qf[4];
  #pragma unroll
  for (int kk = 0; kk < 4; kk++)
    qf[kk] = *(const short8*)(Qp + kk * 32 + grp * 8);

  f32x4 acc_o[8] = {};                            // O^T[dd][q]: 8 dd-frags
  float m_run = -3.0e38f, l_run = 0.0f;
  const float ce = 0.08838834764831845f * 1.4426950408889634f; // 1/sqrt(128)*log2(e)

  const char* Kbh = (const char*)K  + ((size_t)b * 2048 * 2048 + h * 128) * 2;
  const char* Vbh = (const char*)Vt + ((size_t)(b * 2048 + h * 128)) * 2048 * 2;

  auto stage = [&](int buf, int kvt) {
    const int kv0 = kvt * 64;
    #pragma unroll
    for (int u = 0; u < 2; u++) {                  // K: 1024 x 16B chunks
      int c = tid + u * 512;
      int row = c >> 4, slot = c & 15;
      gload_lds16(Kbh + (size_t)(kv0 + row) * 4096 + ((slot ^ (row & 7)) << 4),
                  (char*)Kl[buf] + c * 16);
    }
    #pragma unroll
    for (int u = 0; u < 2; u++) {                  // V: 1024 x 16B chunks
      int c = tid + u * 512;
      int dd = c >> 3, slot = c & 7;
      gload_lds16(Vbh + (size_t)dd * 4096 + kv0 * 2 + ((slot ^ (dd & 7)) << 4),
                  (char*)Vl[buf] + c * 16);
    }
  };

  const int nkv = 2 * qt + 2;
  stage(0, 0);
  __syncthreads();

  for (int kvt = 0; kvt < nkv; kvt++) {
    const int kv0 = kvt * 64;
    const int cur = kvt & 1;
    if (kvt + 1 < nkv) stage(cur ^ 1, kvt + 1);

    if (kv0 <= q0w + 15) {                         // wave has unmasked rows
      const char* Kc = (const char*)Kl[cur];
      const char* Vc = (const char*)Vl[cur];
      // S^T[kv][q] = mfma(K-rows, Q-rows) over d=128
      f32x4 sa[4] = {};
      #pragma unroll
      for (int kk = 0; kk < 4; kk++) {
        #pragma unroll
        for (int mi = 0; mi < 4; mi++) {
          const int krow = mi * 16 + lr;
          short8 kf = *(const short8*)(Kc + krow * 256 + (((kk * 4 + grp) ^ (krow & 7)) << 4));
          sa[mi] = MFMA_BF16(kf, qf[kk], sa[mi]);
        }
      }
      // mask + online softmax; lane holds 16 scores of ONE q-row
      float tmax = -3.0e38f;
      const bool dg = (kv0 + 63 > qrow);
      #pragma unroll
      for (int mi = 0; mi < 4; mi++)
        #pragma unroll
        for (int r = 0; r < 4; r++) {
          float s = sa[mi][r];
          if (dg && (kv0 + mi * 16 + grp * 4 + r > qrow)) s = -3.0e38f;
          sa[mi][r] = s;
          tmax = fmaxf(tmax, s);
        }
      tmax = fmaxf(tmax, __shfl_xor(tmax, 16, 64));
      tmax = fmaxf(tmax, __shfl_xor(tmax, 32, 64));
      const float m_new = fmaxf(m_run, tmax);
      const float alpha = exp2f((m_run - m_new) * ce);
      float psum = 0.0f;
      #pragma unroll
      for (int mi = 0; mi < 4; mi++)
        #pragma unroll
        for (int r = 0; r < 4; r++) {
          float e = exp2f((sa[mi][r] - m_new) * ce);
          sa[mi][r] = e;
          psum += e;
        }
      psum += __shfl_xor(psum, 16, 64);
      psum += __shfl_xor(psum, 32, 64);
      l_run = l_run * alpha + psum;
      m_run = m_new;
      #pragma unroll
      for (int mi = 0; mi < 8; mi++) acc_o[mi] *= alpha;

      // P^T regs -> PV B-operand (split-k); V tile is pre-permuted so the
      // matching A-fragment is one contiguous (swizzled) ds_read_b128.
      short8 pb[2];
      #pragma unroll
      for (int kb = 0; kb < 2; kb++)
        #pragma unroll
        for (int i = 0; i < 4; i++) {
          pb[kb][i]     = (short)f2bf(sa[2 * kb][i]);
          pb[kb][4 + i] = (short)f2bf(sa[2 * kb + 1][i]);
        }
      #pragma unroll
      for (int mi = 0; mi < 8; mi++) {
        const int vrow = mi * 16 + lr;
        #pragma unroll
        for (int kb = 0; kb < 2; kb++) {
          short8 vf = *(const short8*)(Vc + vrow * 128 + (((kb * 4 + grp) ^ (vrow & 7)) << 4));
          acc_o[mi] = MFMA_BF16(vf, pb[kb], acc_o[mi]);
        }
      }
    }
    __syncthreads();
  }

  const float inv_l = 1.0f / l_run;
  u16* Cp = ctx + ((size_t)(b * 2048 + qrow)) * 2048 + h * 128;
  #pragma unroll
  for (int mi = 0; mi < 8; mi++) {
    ushort4 o;
    o.x = f2bf(acc_o[mi][0] * inv_l);
    o.y = f2bf(acc_o[mi][1] * inv_l);
    o.z = f2bf(acc_o[mi][2] * inv_l);
    o.w = f2bf(acc_o[mi][3] * inv_l);
    *(ushort4*)(Cp + mi * 16 + grp * 4) = o;
  }
}

// ---------- launch ----------
extern "C" void kernel_launch(void* const* d_in, const int* in_sizes, int n_in,
                              void* d_out, int out_size, void* d_ws, size_t ws_size,
                              hipStream_t stream) {
  const float* x  = (const float*)d_in[0];
  const float* Wq = (const float*)d_in[1];
  const float* Wk = (const float*)d_in[2];
  const float* Wv = (const float*)d_in[3];
  const float* Wo = (const float*)d_in[4];
  float* out = (float*)d_out;
  char* ws = (char*)d_ws;
  if (ws_size < WS_NEED) return;   // clean failure instead of OOB

  u16* xb    = (u16*)(ws + OFF_XB);
  u16* Wqkvt = (u16*)(ws + OFF_WQKVT);
  u16* Wot   = (u16*)(ws + OFF_WOT);
  u16* Qb    = (u16*)(ws + OFF_Q);
  u16* Kb    = (u16*)(ws + OFF_K);
  u16* Vtb   = (u16*)(ws + OFF_VT);
  u16* ctxb  = (u16*)(ws + OFF_CTX);
  float* ctab = (float*)(ws + OFF_COS);
  float* stab = (float*)(ws + OFF_SIN);

  cast_x_kernel<<<8192, 256, 0, stream>>>(x, xb, 2097152);
  castT_w_kernel<<<dim3(64, 64, 4), dim3(32, 8), 0, stream>>>(Wq, Wk, Wv, Wo, Wqkvt, Wot);
  rope_table_kernel<<<512, 256, 0, stream>>>(ctab, stab);
  gemm_bt_kernel<0><<<dim3(48, 32), 256, 0, stream>>>(xb, Wqkvt, Qb, Kb, Vtb, nullptr, 2048);
  rope_apply_kernel<<<dim3(16384, 2), 256, 0, stream>>>(Qb, Kb, ctab, stab);
  attn_kernel<<<dim3(16, 32), 512, 0, stream>>>(Qb, Kb, Vtb, ctxb);
  gemm_bt_kernel<1><<<dim3(16, 32), 256, 0, stream>>>(ctxb, Wot, nullptr, nullptr, nullptr, out, 2048);
}

// Round 4
// 445.159 us; speedup vs baseline: 2.6762x; 1.0420x over previous
//
#include <hip/hip_runtime.h>
#include <hip/hip_bf16.h>

// ---------- types ----------
typedef __attribute__((ext_vector_type(8))) __bf16 bf16x8;
typedef __attribute__((ext_vector_type(8))) short  short8;
typedef __attribute__((ext_vector_type(4))) float  f32x4;
typedef unsigned short u16;
typedef unsigned int   u32;

__device__ __forceinline__ u16 f2bf(float f) {
  u32 u = __builtin_bit_cast(u32, f);
  u += 0x7fffu + ((u >> 16) & 1u);          // round-to-nearest-even
  return (u16)(u >> 16);
}
__device__ __forceinline__ float bf2f(u16 h) {
  return __builtin_bit_cast(float, (u32)h << 16);
}

#define MFMA_BF16(a, b, c) __builtin_amdgcn_mfma_f32_16x16x32_bf16( \
    __builtin_bit_cast(bf16x8, (a)), __builtin_bit_cast(bf16x8, (b)), (c), 0, 0, 0)

__device__ __forceinline__ void gload_lds16(const void* g, void* l) {
  __builtin_amdgcn_global_load_lds(
      (const __attribute__((address_space(1))) void*)g,
      (__attribute__((address_space(3))) void*)l, 16, 0, 0);
}

// ---------- problem constants ----------
#define SEQ   2048
#define DMODEL 2048
#define NH    16
#define HD    128

// ---------- workspace layout (bytes) ----------
static constexpr size_t SZ_MAT   = 4096ull * 2048 * 2;        // (b*s, d) bf16 = 16 MiB
static constexpr size_t OFF_XB   = 0;
static constexpr size_t OFF_WQKVT= OFF_XB   + SZ_MAT;          // Wq^T|Wk^T|Wv^T
static constexpr size_t OFF_WOT  = OFF_WQKVT+ 3ull*2048*2048*2;
static constexpr size_t OFF_Q    = OFF_WOT  + 2048ull*2048*2;
static constexpr size_t OFF_K    = OFF_Q    + SZ_MAT;
static constexpr size_t OFF_VT   = OFF_K    + SZ_MAT;          // Vp[b*2048+h*128+dd][s_perm]
static constexpr size_t OFF_CTX  = OFF_VT   + SZ_MAT;
static constexpr size_t OFF_COS  = OFF_CTX  + SZ_MAT;
static constexpr size_t OFF_SIN  = OFF_COS  + 2048ull*64*4;
static constexpr size_t WS_NEED  = OFF_SIN  + 2048ull*64*4;    // ~113 MiB

// ---------- prep kernels ----------
__global__ void cast_x_kernel(const float* __restrict__ x, u16* __restrict__ xb, int n4) {
  int id = blockIdx.x * blockDim.x + threadIdx.x;
  if (id >= n4) return;
  float4 v = ((const float4*)x)[id];
  ushort4 o;
  o.x = f2bf(v.x); o.y = f2bf(v.y); o.z = f2bf(v.z); o.w = f2bf(v.w);
  ((ushort4*)xb)[id] = o;
}

__global__ void castT_w_kernel(const float* __restrict__ W0, const float* __restrict__ W1,
                               const float* __restrict__ W2, const float* __restrict__ W3,
                               u16* __restrict__ Wqkvt, u16* __restrict__ Wot) {
  __shared__ float tile[32][33];
  int z = blockIdx.z;
  const float* W = (z == 0) ? W0 : (z == 1) ? W1 : (z == 2) ? W2 : W3;
  u16* Out = (z < 3) ? (Wqkvt + (size_t)z * 2048 * 2048) : Wot;
  int n0 = blockIdx.x * 32, k0 = blockIdx.y * 32;
  int tx = threadIdx.x, ty = threadIdx.y;   // (32,8)
  #pragma unroll
  for (int i = 0; i < 4; i++)
    tile[ty + 8 * i][tx] = W[(size_t)(k0 + ty + 8 * i) * 2048 + n0 + tx];
  __syncthreads();
  #pragma unroll
  for (int i = 0; i < 4; i++)
    Out[(size_t)(n0 + ty + 8 * i) * 2048 + k0 + tx] = f2bf(tile[tx][ty + 8 * i]);
}

__global__ void rope_table_kernel(float* __restrict__ ct, float* __restrict__ st) {
  int id = blockIdx.x * blockDim.x + threadIdx.x;  // 2048*64
  int pos = id >> 6, j = id & 63;
  float inv = exp2f(-(float)j * (13.287712379549449f / 64.0f));
  float a = (float)pos * inv;
  ct[id] = cosf(a);
  st[id] = sinf(a);
}

__global__ void rope_apply_kernel(u16* __restrict__ Q, u16* __restrict__ K,
                                  const float* __restrict__ ct, const float* __restrict__ st) {
  int id = blockIdx.x * blockDim.x + threadIdx.x;    // < 4096*16*64
  u16* P = blockIdx.y ? K : Q;
  int row = id >> 10;
  int r = id & 1023;
  int hh = r >> 6, j = r & 63;
  int pos = row & 2047;
  size_t base = (size_t)row * 2048 + hh * 128 + j;
  float x1 = bf2f(P[base]), x2 = bf2f(P[base + 64]);
  float c = ct[pos * 64 + j], s = st[pos * 64 + j];
  P[base]      = f2bf(x1 * c - x2 * s);
  P[base + 64] = f2bf(x2 * c + x1 * s);
}

// ======================================================================
// 256x256 8-phase GEMM (T2+T3+T4+T5): C[4096 x 6144] = A @ Bt^T, K=2048.
// 8 waves (2M x 4N), BK=64, 2 K-tiles/iteration, 128 KiB LDS double-buffer.
// Fused QKV epilogue (Q,K row-major bf16; V transposed + kv-permuted).
// LDS geometry per operand per buffer: [256 rows][8 slots of 16B] (128B rows).
// Swizzle: slot' = slot ^ (row&7); staging = linear dest + inverse-swz global
// source (involution, rule #21). 8 consecutive lanes -> 8 distinct slots.
// ======================================================================
#define SB __builtin_amdgcn_sched_barrier(0)
#define BAR()   do { SB; __builtin_amdgcn_s_barrier(); SB; } while (0)
#define VMCNT4() do { SB; asm volatile("s_waitcnt vmcnt(4)" ::: "memory"); SB; } while (0)
#define VMCNT0() do { SB; asm volatile("s_waitcnt vmcnt(0)" ::: "memory"); SB; } while (0)

#define STAGE8(gb, kt, H, lb)                                                  \
  do { _Pragma("unroll")                                                       \
    for (int u = 0; u < 2; u++) {                                              \
      int c = tid + u * 512;                                                   \
      int rr = c >> 3, sl = c & 7;                                             \
      gload_lds16((gb) + (size_t)((H) * 128 + rr) * 4096 + (size_t)(kt) * 128  \
                       + ((sl ^ (rr & 7)) << 4),                               \
                  (lb) + (H) * 16384 + c * 16);                                \
    } } while (0)

#define LDA8(lb, MG)                                                           \
  do { _Pragma("unroll")                                                       \
    for (int mi = 0; mi < 4; mi++) {                                           \
      af[mi][0] = *(const short8*)((lb) + aoff + ((MG) + mi) * 2048 + sw0);    \
      af[mi][1] = *(const short8*)((lb) + aoff + ((MG) + mi) * 2048 + sw1);    \
    } } while (0)

#define LDB4(lb, NG)                                                           \
  do { _Pragma("unroll")                                                       \
    for (int nj = 0; nj < 2; nj++) {                                           \
      bfr[(NG) + nj][0] = *(const short8*)((lb) + boff + ((NG) + nj) * 2048 + sw0); \
      bfr[(NG) + nj][1] = *(const short8*)((lb) + boff + ((NG) + nj) * 2048 + sw1); \
    } } while (0)

#define MMQ(MG, NG)                                                            \
  do {                                                                         \
    __builtin_amdgcn_s_setprio(1);                                             \
    _Pragma("unroll")                                                          \
    for (int mi = 0; mi < 4; mi++) {                                           \
      _Pragma("unroll")                                                        \
      for (int nj = 0; nj < 2; nj++) {                                         \
        acc[(MG) + mi][(NG) + nj] =                                            \
            MFMA_BF16(af[mi][0], bfr[(NG) + nj][0], acc[(MG) + mi][(NG) + nj]);\
        acc[(MG) + mi][(NG) + nj] =                                            \
            MFMA_BF16(af[mi][1], bfr[(NG) + nj][1], acc[(MG) + mi][(NG) + nj]);\
      }                                                                        \
    }                                                                          \
    __builtin_amdgcn_s_setprio(0);                                             \
  } while (0)

// One iteration = K-tiles (2t) from buf0 then (2t+1) from buf1.
// Stage slots (issue phase -> half): P1:A.h0(k1) P2:A.h1(k1) P3:B.h0(k2)
// P4:A.h0(k2) P5:A.h1(k2) P6:B.h1(k2) P7:B.h0(k3) P8:B.h1(k3).
// Each stage issues after the target region's last reader's end-barrier.
// vmcnt(4) at P4/P8: 12 loads outstanding, waits the 8 oldest (= next K-tile).
#define GEMM8_ITER(K1v, K2v, K3v, LAST)                                        \
  do {                                                                         \
    LDA8(A0p, 0); LDB4(B0p, 0);                                                \
    STAGE8(Ab, (K1v), 0, A1p);                                                 \
    BAR(); MMQ(0, 0); BAR();                                                   \
    LDB4(B0p, 2);                                                              \
    STAGE8(Ab, (K1v), 1, A1p);                                                 \
    BAR(); MMQ(0, 2); BAR();                                                   \
    LDA8(A0p, 4);                                                              \
    if (!(LAST)) STAGE8(Bb, (K2v), 0, B0p);                                    \
    BAR(); MMQ(4, 2); BAR();                                                   \
    if (!(LAST)) STAGE8(Ab, (K2v), 0, A0p);                                    \
    if (LAST) { VMCNT0(); } else { VMCNT4(); }                                 \
    BAR(); MMQ(4, 0); BAR();                                                   \
    LDA8(A1p, 0); LDB4(B1p, 0);                                                \
    if (!(LAST)) STAGE8(Ab, (K2v), 1, A0p);                                    \
    BAR(); MMQ(0, 0); BAR();                                                   \
    LDB4(B1p, 2);                                                              \
    if (!(LAST)) STAGE8(Bb, (K2v), 1, B0p);                                    \
    BAR(); MMQ(0, 2); BAR();                                                   \
    LDA8(A1p, 4);                                                              \
    if (!(LAST)) STAGE8(Bb, (K3v), 0, B1p);                                    \
    BAR(); MMQ(4, 2); BAR();                                                   \
    if (!(LAST)) { STAGE8(Bb, (K3v), 1, B1p); VMCNT4(); }                      \
    BAR(); MMQ(4, 0); BAR();                                                   \
  } while (0)

__global__ __launch_bounds__(512, 2)
void gemm8_qkv_kernel(const u16* __restrict__ A, const u16* __restrict__ Bt,
                      u16* __restrict__ Qo, u16* __restrict__ Ko,
                      u16* __restrict__ Vto) {
  __shared__ u16 Asm[2][16384];   // [buf][256r][64c] 32 KB each
  __shared__ u16 Bsm[2][16384];
  const int tid = threadIdx.x;
  const int lane = tid & 63, w = tid >> 6;
  const int grp = lane >> 4, lr = lane & 15;
  const int wm = w >> 2, wn = w & 3;          // 2 x 4 waves
  const int bm = blockIdx.y, bn = blockIdx.x; // 16 x 24

  const char* Ab = (const char*)A + (size_t)bm * 256 * 4096;
  const char* Bb = (const char*)Bt + (size_t)bn * 256 * 4096;
  char* A0p = (char*)Asm[0]; char* A1p = (char*)Asm[1];
  char* B0p = (char*)Bsm[0]; char* B1p = (char*)Bsm[1];

  f32x4 acc[8][4] = {};
  short8 af[4][2], bfr[4][2];
  const int aoff = wm * 16384 + lr * 128;     // A row base (wave m-origin + lr)
  const int boff = wn * 8192 + lr * 128;      // B row base (wave n-origin + lr)
  const int sw0 = ((grp    ) ^ (lr & 7)) << 4;
  const int sw1 = ((grp + 4) ^ (lr & 7)) << 4;

  // prologue: k0 fully + k1 B-halves; wait k0 (8 oldest of 12)
  STAGE8(Ab, 0, 0, A0p);
  STAGE8(Ab, 0, 1, A0p);
  STAGE8(Bb, 0, 0, B0p);
  STAGE8(Bb, 0, 1, B0p);
  STAGE8(Bb, 1, 0, B1p);
  STAGE8(Bb, 1, 1, B1p);
  VMCNT4();
  BAR();

  #pragma unroll 1
  for (int t = 0; t < 15; ++t) {
    GEMM8_ITER(2 * t + 1, 2 * t + 2, 2 * t + 3, false);
  }
  GEMM8_ITER(31, 0, 0, true);

  // epilogue: C/D layout col = lane&15, row = 4*(lane>>4)+reg
  const int seg = bn >> 3;                    // 0=Q 1=K 2=V (2048-col segments)
  const int row0 = bm * 256 + wm * 128 + grp * 4;
  const int col0 = (bn & 7) * 256 + wn * 64 + lr;
  if (seg < 2) {
    u16* O = seg ? Ko : Qo;
    #pragma unroll
    for (int ai = 0; ai < 8; ai++)
      #pragma unroll
      for (int nj = 0; nj < 4; nj++) {
        int col = col0 + nj * 16;
        int row = row0 + ai * 16;
        #pragma unroll
        for (int r = 0; r < 4; r++)
          O[(size_t)(row + r) * 2048 + col] = f2bf(acc[ai][nj][r]);
      }
  } else {
    // V: write Vp[(b*2048 + h*128+dd)][s_perm]; 4 regs = 4 consecutive s.
    #pragma unroll
    for (int ai = 0; ai < 8; ai++) {
      int row = row0 + ai * 16;               // = b*2048 + s (s multiple of 4)
      int b = row >> 11, s = row & 2047;
      int sp = (s & ~31) | (((s >> 2) & 3) << 3) | (((s >> 4) & 1) << 2);
      #pragma unroll
      for (int nj = 0; nj < 4; nj++) {
        int colv = col0 + nj * 16;            // h*128 + dd
        ushort4 o;
        o.x = f2bf(acc[ai][nj][0]); o.y = f2bf(acc[ai][nj][1]);
        o.z = f2bf(acc[ai][nj][2]); o.w = f2bf(acc[ai][nj][3]);
        *(ushort4*)(Vto + (size_t)(b * 2048 + colv) * 2048 + sp) = o;
      }
    }
  }
}

// ---------- out-proj GEMM: 128x128 tile, 4 waves (old structure) ----------
__global__ __launch_bounds__(256)
void gemm_bt_kernel(const u16* __restrict__ A, const u16* __restrict__ Bt,
                    float* __restrict__ Co, int K) {
  __shared__ u16 Al[128 * 32];
  __shared__ u16 Bl[128 * 32];
  const int tid = threadIdx.x;
  const int lane = tid & 63;
  const int w = tid >> 6;
  const int grp = lane >> 4, lr = lane & 15;
  const int bm = blockIdx.y, bn = blockIdx.x;
  const int wm = w >> 1, wn = w & 1;
  f32x4 acc[4][4] = {};
  const char* Ab = (const char*)(A + (size_t)bm * 128 * K);
  const char* Bb = (const char*)(Bt + (size_t)bn * 128 * K);
  const int c0 = tid, c1 = tid + 256;
  const int rA0 = c0 >> 2, cb0 = (c0 & 3) * 16;
  const int rA1 = c1 >> 2, cb1 = (c1 & 3) * 16;

  for (int kt = 0; kt < K; kt += 32) {
    gload_lds16(Ab + (size_t)rA0 * K * 2 + kt * 2 + cb0, (char*)Al + c0 * 16);
    gload_lds16(Ab + (size_t)rA1 * K * 2 + kt * 2 + cb1, (char*)Al + c1 * 16);
    gload_lds16(Bb + (size_t)rA0 * K * 2 + kt * 2 + cb0, (char*)Bl + c0 * 16);
    gload_lds16(Bb + (size_t)rA1 * K * 2 + kt * 2 + cb1, (char*)Bl + c1 * 16);
    __syncthreads();
    short8 af[4], bf[4];
    #pragma unroll
    for (int mi = 0; mi < 4; mi++)
      af[mi] = *(const short8*)(Al + (wm * 64 + mi * 16 + lr) * 32 + grp * 8);
    #pragma unroll
    for (int nj = 0; nj < 4; nj++)
      bf[nj] = *(const short8*)(Bl + (wn * 64 + nj * 16 + lr) * 32 + grp * 8);
    #pragma unroll
    for (int mi = 0; mi < 4; mi++)
      #pragma unroll
      for (int nj = 0; nj < 4; nj++)
        acc[mi][nj] = MFMA_BF16(af[mi], bf[nj], acc[mi][nj]);
    __syncthreads();
  }

  const int rowBase = bm * 128 + wm * 64 + grp * 4;
  const int colBase = bn * 128 + wn * 64 + lr;
  #pragma unroll
  for (int mi = 0; mi < 4; mi++)
    #pragma unroll
    for (int nj = 0; nj < 4; nj++)
      #pragma unroll
      for (int r = 0; r < 4; r++)
        Co[(size_t)(rowBase + mi * 16 + r) * 2048 + colBase + nj * 16] = acc[mi][nj][r];
}

// ---------- flash attention (causal), LDS-staged K/V, double-buffered ----------
__global__ __launch_bounds__(512, 4)
void attn_kernel(const u16* __restrict__ Q, const u16* __restrict__ K,
                 const u16* __restrict__ Vt, u16* __restrict__ ctx) {
  __shared__ u16 Kl[2][64 * 128];   // 16 KB each
  __shared__ u16 Vl[2][128 * 64];   // 16 KB each
  const int qt = blockIdx.x, bh = blockIdx.y;
  const int b = bh >> 4, h = bh & 15;
  const int tid = threadIdx.x;
  const int w = tid >> 6, lane = tid & 63;
  const int grp = lane >> 4, lr = lane & 15;
  const int q0w = qt * 128 + w * 16;
  const int qrow = q0w + lr;
  const u16* Qp = Q + ((size_t)(b * 2048 + qrow)) * 2048 + h * 128;
  short8 qf[4];
  #pragma unroll
  for (int kk = 0; kk < 4; kk++)
    qf[kk] = *(const short8*)(Qp + kk * 32 + grp * 8);

  f32x4 acc_o[8] = {};                            // O^T[dd][q]: 8 dd-frags
  float m_run = -3.0e38f, l_run = 0.0f;
  const float ce = 0.08838834764831845f * 1.4426950408889634f; // 1/sqrt(128)*log2(e)

  const char* Kbh = (const char*)K  + ((size_t)b * 2048 * 2048 + h * 128) * 2;
  const char* Vbh = (const char*)Vt + ((size_t)(b * 2048 + h * 128)) * 2048 * 2;

  auto stage = [&](int buf, int kvt) {
    const int kv0 = kvt * 64;
    #pragma unroll
    for (int u = 0; u < 2; u++) {                  // K: 1024 x 16B chunks
      int c = tid + u * 512;
      int row = c >> 4, slot = c & 15;
      gload_lds16(Kbh + (size_t)(kv0 + row) * 4096 + ((slot ^ (row & 7)) << 4),
                  (char*)Kl[buf] + c * 16);
    }
    #pragma unroll
    for (int u = 0; u < 2; u++) {                  // V: 1024 x 16B chunks
      int c = tid + u * 512;
      int dd = c >> 3, slot = c & 7;
      gload_lds16(Vbh + (size_t)dd * 4096 + kv0 * 2 + ((slot ^ (dd & 7)) << 4),
                  (char*)Vl[buf] + c * 16);
    }
  };

  const int nkv = 2 * qt + 2;
  stage(0, 0);
  __syncthreads();

  for (int kvt = 0; kvt < nkv; kvt++) {
    const int kv0 = kvt * 64;
    const int cur = kvt & 1;
    if (kvt + 1 < nkv) stage(cur ^ 1, kvt + 1);

    if (kv0 <= q0w + 15) {                         // wave has unmasked rows
      const char* Kc = (const char*)Kl[cur];
      const char* Vc = (const char*)Vl[cur];
      f32x4 sa[4] = {};
      #pragma unroll
      for (int kk = 0; kk < 4; kk++) {
        #pragma unroll
        for (int mi = 0; mi < 4; mi++) {
          const int krow = mi * 16 + lr;
          short8 kf = *(const short8*)(Kc + krow * 256 + (((kk * 4 + grp) ^ (krow & 7)) << 4));
          sa[mi] = MFMA_BF16(kf, qf[kk], sa[mi]);
        }
      }
      float tmax = -3.0e38f;
      const bool dg = (kv0 + 63 > qrow);
      #pragma unroll
      for (int mi = 0; mi < 4; mi++)
        #pragma unroll
        for (int r = 0; r < 4; r++) {
          float s = sa[mi][r];
          if (dg && (kv0 + mi * 16 + grp * 4 + r > qrow)) s = -3.0e38f;
          sa[mi][r] = s;
          tmax = fmaxf(tmax, s);
        }
      tmax = fmaxf(tmax, __shfl_xor(tmax, 16, 64));
      tmax = fmaxf(tmax, __shfl_xor(tmax, 32, 64));
      const float m_new = fmaxf(m_run, tmax);
      const float alpha = exp2f((m_run - m_new) * ce);
      float psum = 0.0f;
      #pragma unroll
      for (int mi = 0; mi < 4; mi++)
        #pragma unroll
        for (int r = 0; r < 4; r++) {
          float e = exp2f((sa[mi][r] - m_new) * ce);
          sa[mi][r] = e;
          psum += e;
        }
      psum += __shfl_xor(psum, 16, 64);
      psum += __shfl_xor(psum, 32, 64);
      l_run = l_run * alpha + psum;
      m_run = m_new;
      #pragma unroll
      for (int mi = 0; mi < 8; mi++) acc_o[mi] *= alpha;

      short8 pb[2];
      #pragma unroll
      for (int kb = 0; kb < 2; kb++)
        #pragma unroll
        for (int i = 0; i < 4; i++) {
          pb[kb][i]     = (short)f2bf(sa[2 * kb][i]);
          pb[kb][4 + i] = (short)f2bf(sa[2 * kb + 1][i]);
        }
      #pragma unroll
      for (int mi = 0; mi < 8; mi++) {
        const int vrow = mi * 16 + lr;
        #pragma unroll
        for (int kb = 0; kb < 2; kb++) {
          short8 vf = *(const short8*)(Vc + vrow * 128 + (((kb * 4 + grp) ^ (vrow & 7)) << 4));
          acc_o[mi] = MFMA_BF16(vf, pb[kb], acc_o[mi]);
        }
      }
    }
    __syncthreads();
  }

  const float inv_l = 1.0f / l_run;
  u16* Cp = ctx + ((size_t)(b * 2048 + qrow)) * 2048 + h * 128;
  #pragma unroll
  for (int mi = 0; mi < 8; mi++) {
    ushort4 o;
    o.x = f2bf(acc_o[mi][0] * inv_l);
    o.y = f2bf(acc_o[mi][1] * inv_l);
    o.z = f2bf(acc_o[mi][2] * inv_l);
    o.w = f2bf(acc_o[mi][3] * inv_l);
    *(ushort4*)(Cp + mi * 16 + grp * 4) = o;
  }
}

// ---------- launch ----------
extern "C" void kernel_launch(void* const* d_in, const int* in_sizes, int n_in,
                              void* d_out, int out_size, void* d_ws, size_t ws_size,
                              hipStream_t stream) {
  const float* x  = (const float*)d_in[0];
  const float* Wq = (const float*)d_in[1];
  const float* Wk = (const float*)d_in[2];
  const float* Wv = (const float*)d_in[3];
  const float* Wo = (const float*)d_in[4];
  float* out = (float*)d_out;
  char* ws = (char*)d_ws;
  if (ws_size < WS_NEED) return;

  u16* xb    = (u16*)(ws + OFF_XB);
  u16* Wqkvt = (u16*)(ws + OFF_WQKVT);
  u16* Wot   = (u16*)(ws + OFF_WOT);
  u16* Qb    = (u16*)(ws + OFF_Q);
  u16* Kb    = (u16*)(ws + OFF_K);
  u16* Vtb   = (u16*)(ws + OFF_VT);
  u16* ctxb  = (u16*)(ws + OFF_CTX);
  float* ctab = (float*)(ws + OFF_COS);
  float* stab = (float*)(ws + OFF_SIN);

  cast_x_kernel<<<8192, 256, 0, stream>>>(x, xb, 2097152);
  castT_w_kernel<<<dim3(64, 64, 4), dim3(32, 8), 0, stream>>>(Wq, Wk, Wv, Wo, Wqkvt, Wot);
  rope_table_kernel<<<512, 256, 0, stream>>>(ctab, stab);
  gemm8_qkv_kernel<<<dim3(24, 16), 512, 0, stream>>>(xb, Wqkvt, Qb, Kb, Vtb);
  rope_apply_kernel<<<dim3(16384, 2), 256, 0, stream>>>(Qb, Kb, ctab, stab);
  attn_kernel<<<dim3(16, 32), 512, 0, stream>>>(Qb, Kb, Vtb, ctxb);
  gemm_bt_kernel<<<dim3(16, 32), 256, 0, stream>>>(ctxb, Wot, out, 2048);
}

// Round 10
// 420.261 us; speedup vs baseline: 2.8348x; 1.0592x over previous
//
#include <hip/hip_runtime.h>
#include <hip/hip_bf16.h>

// ---------- types ----------
typedef __attribute__((ext_vector_type(8))) __bf16 bf16x8;
typedef __attribute__((ext_vector_type(8))) short  short8;
typedef __attribute__((ext_vector_type(4))) float  f32x4;
typedef unsigned short u16;
typedef unsigned int   u32;

__device__ __forceinline__ u16 f2bf(float f) {
  u32 u = __builtin_bit_cast(u32, f);
  u += 0x7fffu + ((u >> 16) & 1u);          // round-to-nearest-even
  return (u16)(u >> 16);
}
__device__ __forceinline__ float bf2f(u16 h) {
  return __builtin_bit_cast(float, (u32)h << 16);
}

#define MFMA_BF16(a, b, c) __builtin_amdgcn_mfma_f32_16x16x32_bf16( \
    __builtin_bit_cast(bf16x8, (a)), __builtin_bit_cast(bf16x8, (b)), (c), 0, 0, 0)

__device__ __forceinline__ void gload_lds16(const void* g, void* l) {
  __builtin_amdgcn_global_load_lds(
      (const __attribute__((address_space(1))) void*)g,
      (__attribute__((address_space(3))) void*)l, 16, 0, 0);
}

// ---------- problem constants ----------
#define SEQ   2048
#define DMODEL 2048
#define NH    16
#define HD    128

// ---------- workspace layout (bytes) ----------
static constexpr size_t SZ_MAT   = 4096ull * 2048 * 2;        // (b*s, d) bf16 = 16 MiB
static constexpr size_t OFF_XB   = 0;
static constexpr size_t OFF_WQKVT= OFF_XB   + SZ_MAT;          // Wq^T|Wk^T|Wv^T
static constexpr size_t OFF_WOT  = OFF_WQKVT+ 3ull*2048*2048*2;
static constexpr size_t OFF_Q    = OFF_WOT  + 2048ull*2048*2;
static constexpr size_t OFF_K    = OFF_Q    + SZ_MAT;
static constexpr size_t OFF_VT   = OFF_K    + SZ_MAT;          // Vp[b*2048+h*128+dd][s_perm]
static constexpr size_t OFF_CTX  = OFF_VT   + SZ_MAT;
static constexpr size_t OFF_COS  = OFF_CTX  + SZ_MAT;
static constexpr size_t OFF_SIN  = OFF_COS  + 2048ull*64*4;
static constexpr size_t WS_NEED  = OFF_SIN  + 2048ull*64*4;    // ~113 MiB

// ---------- prep kernels ----------
__global__ void cast_x_kernel(const float* __restrict__ x, u16* __restrict__ xb, int n4) {
  int id = blockIdx.x * blockDim.x + threadIdx.x;
  if (id >= n4) return;
  float4 v = ((const float4*)x)[id];
  ushort4 o;
  o.x = f2bf(v.x); o.y = f2bf(v.y); o.z = f2bf(v.z); o.w = f2bf(v.w);
  ((ushort4*)xb)[id] = o;
}

__global__ void castT_w_kernel(const float* __restrict__ W0, const float* __restrict__ W1,
                               const float* __restrict__ W2, const float* __restrict__ W3,
                               u16* __restrict__ Wqkvt, u16* __restrict__ Wot) {
  __shared__ float tile[32][33];
  int z = blockIdx.z;
  const float* W = (z == 0) ? W0 : (z == 1) ? W1 : (z == 2) ? W2 : W3;
  u16* Out = (z < 3) ? (Wqkvt + (size_t)z * 2048 * 2048) : Wot;
  int n0 = blockIdx.x * 32, k0 = blockIdx.y * 32;
  int tx = threadIdx.x, ty = threadIdx.y;   // (32,8)
  #pragma unroll
  for (int i = 0; i < 4; i++)
    tile[ty + 8 * i][tx] = W[(size_t)(k0 + ty + 8 * i) * 2048 + n0 + tx];
  __syncthreads();
  #pragma unroll
  for (int i = 0; i < 4; i++)
    Out[(size_t)(n0 + ty + 8 * i) * 2048 + k0 + tx] = f2bf(tile[tx][ty + 8 * i]);
}

__global__ void rope_table_kernel(float* __restrict__ ct, float* __restrict__ st) {
  int id = blockIdx.x * blockDim.x + threadIdx.x;  // 2048*64
  int pos = id >> 6, j = id & 63;
  float inv = exp2f(-(float)j * (13.287712379549449f / 64.0f));
  float a = (float)pos * inv;
  ct[id] = cosf(a);
  st[id] = sinf(a);
}

__global__ void rope_apply_kernel(u16* __restrict__ Q, u16* __restrict__ K,
                                  const float* __restrict__ ct, const float* __restrict__ st) {
  int id = blockIdx.x * blockDim.x + threadIdx.x;    // < 4096*16*64
  u16* P = blockIdx.y ? K : Q;
  int row = id >> 10;
  int r = id & 1023;
  int hh = r >> 6, j = r & 63;
  int pos = row & 2047;
  size_t base = (size_t)row * 2048 + hh * 128 + j;
  float x1 = bf2f(P[base]), x2 = bf2f(P[base + 64]);
  float c = ct[pos * 64 + j], s = st[pos * 64 + j];
  P[base]      = f2bf(x1 * c - x2 * s);
  P[base + 64] = f2bf(x2 * c + x1 * s);
}

// ======================================================================
// 256x256 8-phase GEMM (T2+T3+T4+T5): C[4096 x 6144] = A @ Bt^T, K=2048.
// ======================================================================
#define SB __builtin_amdgcn_sched_barrier(0)
#define BAR()   do { SB; __builtin_amdgcn_s_barrier(); SB; } while (0)
#define VMCNT4() do { SB; asm volatile("s_waitcnt vmcnt(4)" ::: "memory"); SB; } while (0)
#define VMCNT0() do { SB; asm volatile("s_waitcnt vmcnt(0)" ::: "memory"); SB; } while (0)

#define STAGE8(gb, kt, H, lb)                                                  \
  do { _Pragma("unroll")                                                       \
    for (int u = 0; u < 2; u++) {                                              \
      int c = tid + u * 512;                                                   \
      int rr = c >> 3, sl = c & 7;                                             \
      gload_lds16((gb) + (size_t)((H) * 128 + rr) * 4096 + (size_t)(kt) * 128  \
                       + ((sl ^ (rr & 7)) << 4),                               \
                  (lb) + (H) * 16384 + c * 16);                                \
    } } while (0)

#define LDA8(lb, MG)                                                           \
  do { _Pragma("unroll")                                                       \
    for (int mi = 0; mi < 4; mi++) {                                           \
      af[mi][0] = *(const short8*)((lb) + aoff + ((MG) + mi) * 2048 + sw0);    \
      af[mi][1] = *(const short8*)((lb) + aoff + ((MG) + mi) * 2048 + sw1);    \
    } } while (0)

#define LDB4(lb, NG)                                                           \
  do { _Pragma("unroll")                                                       \
    for (int nj = 0; nj < 2; nj++) {                                           \
      bfr[(NG) + nj][0] = *(const short8*)((lb) + boff + ((NG) + nj) * 2048 + sw0); \
      bfr[(NG) + nj][1] = *(const short8*)((lb) + boff + ((NG) + nj) * 2048 + sw1); \
    } } while (0)

#define MMQ(MG, NG)                                                            \
  do {                                                                         \
    __builtin_amdgcn_s_setprio(1);                                             \
    _Pragma("unroll")                                                          \
    for (int mi = 0; mi < 4; mi++) {                                           \
      _Pragma("unroll")                                                        \
      for (int nj = 0; nj < 2; nj++) {                                         \
        acc[(MG) + mi][(NG) + nj] =                                            \
            MFMA_BF16(af[mi][0], bfr[(NG) + nj][0], acc[(MG) + mi][(NG) + nj]);\
        acc[(MG) + mi][(NG) + nj] =                                            \
            MFMA_BF16(af[mi][1], bfr[(NG) + nj][1], acc[(MG) + mi][(NG) + nj]);\
      }                                                                        \
    }                                                                          \
    __builtin_amdgcn_s_setprio(0);                                             \
  } while (0)

#define GEMM8_ITER(K1v, K2v, K3v, LAST)                                        \
  do {                                                                         \
    LDA8(A0p, 0); LDB4(B0p, 0);                                                \
    STAGE8(Ab, (K1v), 0, A1p);                                                 \
    BAR(); MMQ(0, 0); BAR();                                                   \
    LDB4(B0p, 2);                                                              \
    STAGE8(Ab, (K1v), 1, A1p);                                                 \
    BAR(); MMQ(0, 2); BAR();                                                   \
    LDA8(A0p, 4);                                                              \
    if (!(LAST)) STAGE8(Bb, (K2v), 0, B0p);                                    \
    BAR(); MMQ(4, 2); BAR();                                                   \
    if (!(LAST)) STAGE8(Ab, (K2v), 0, A0p);                                    \
    if (LAST) { VMCNT0(); } else { VMCNT4(); }                                 \
    BAR(); MMQ(4, 0); BAR();                                                   \
    LDA8(A1p, 0); LDB4(B1p, 0);                                                \
    if (!(LAST)) STAGE8(Ab, (K2v), 1, A0p);                                    \
    BAR(); MMQ(0, 0); BAR();                                                   \
    LDB4(B1p, 2);                                                              \
    if (!(LAST)) STAGE8(Bb, (K2v), 1, B0p);                                    \
    BAR(); MMQ(0, 2); BAR();                                                   \
    LDA8(A1p, 4);                                                              \
    if (!(LAST)) STAGE8(Bb, (K3v), 0, B1p);                                    \
    BAR(); MMQ(4, 2); BAR();                                                   \
    if (!(LAST)) { STAGE8(Bb, (K3v), 1, B1p); VMCNT4(); }                      \
    BAR(); MMQ(4, 0); BAR();                                                   \
  } while (0)

__global__ __launch_bounds__(512, 2)
void gemm8_qkv_kernel(const u16* __restrict__ A, const u16* __restrict__ Bt,
                      u16* __restrict__ Qo, u16* __restrict__ Ko,
                      u16* __restrict__ Vto) {
  __shared__ u16 Asm[2][16384];   // [buf][256r][64c] 32 KB each
  __shared__ u16 Bsm[2][16384];
  const int tid = threadIdx.x;
  const int lane = tid & 63, w = tid >> 6;
  const int grp = lane >> 4, lr = lane & 15;
  const int wm = w >> 2, wn = w & 3;          // 2 x 4 waves
  const int bm = blockIdx.y, bn = blockIdx.x; // 16 x 24

  const char* Ab = (const char*)A + (size_t)bm * 256 * 4096;
  const char* Bb = (const char*)Bt + (size_t)bn * 256 * 4096;
  char* A0p = (char*)Asm[0]; char* A1p = (char*)Asm[1];
  char* B0p = (char*)Bsm[0]; char* B1p = (char*)Bsm[1];

  f32x4 acc[8][4] = {};
  short8 af[4][2], bfr[4][2];
  const int aoff = wm * 16384 + lr * 128;
  const int boff = wn * 8192 + lr * 128;
  const int sw0 = ((grp    ) ^ (lr & 7)) << 4;
  const int sw1 = ((grp + 4) ^ (lr & 7)) << 4;

  STAGE8(Ab, 0, 0, A0p);
  STAGE8(Ab, 0, 1, A0p);
  STAGE8(Bb, 0, 0, B0p);
  STAGE8(Bb, 0, 1, B0p);
  STAGE8(Bb, 1, 0, B1p);
  STAGE8(Bb, 1, 1, B1p);
  VMCNT4();
  BAR();

  #pragma unroll 1
  for (int t = 0; t < 15; ++t) {
    GEMM8_ITER(2 * t + 1, 2 * t + 2, 2 * t + 3, false);
  }
  GEMM8_ITER(31, 0, 0, true);

  const int seg = bn >> 3;                    // 0=Q 1=K 2=V (2048-col segments)
  const int row0 = bm * 256 + wm * 128 + grp * 4;
  const int col0 = (bn & 7) * 256 + wn * 64 + lr;
  if (seg < 2) {
    u16* O = seg ? Ko : Qo;
    #pragma unroll
    for (int ai = 0; ai < 8; ai++)
      #pragma unroll
      for (int nj = 0; nj < 4; nj++) {
        int col = col0 + nj * 16;
        int row = row0 + ai * 16;
        #pragma unroll
        for (int r = 0; r < 4; r++)
          O[(size_t)(row + r) * 2048 + col] = f2bf(acc[ai][nj][r]);
      }
  } else {
    #pragma unroll
    for (int ai = 0; ai < 8; ai++) {
      int row = row0 + ai * 16;               // = b*2048 + s (s multiple of 4)
      int b = row >> 11, s = row & 2047;
      int sp = (s & ~31) | (((s >> 2) & 3) << 3) | (((s >> 4) & 1) << 2);
      #pragma unroll
      for (int nj = 0; nj < 4; nj++) {
        int colv = col0 + nj * 16;            // h*128 + dd
        ushort4 o;
        o.x = f2bf(acc[ai][nj][0]); o.y = f2bf(acc[ai][nj][1]);
        o.z = f2bf(acc[ai][nj][2]); o.w = f2bf(acc[ai][nj][3]);
        *(ushort4*)(Vto + (size_t)(b * 2048 + colv) * 2048 + sp) = o;
      }
    }
  }
}

// ---------- out-proj GEMM: 128x128 tile, 4 waves ----------
__global__ __launch_bounds__(256)
void gemm_bt_kernel(const u16* __restrict__ A, const u16* __restrict__ Bt,
                    float* __restrict__ Co, int K) {
  __shared__ u16 Al[128 * 32];
  __shared__ u16 Bl[128 * 32];
  const int tid = threadIdx.x;
  const int lane = tid & 63;
  const int w = tid >> 6;
  const int grp = lane >> 4, lr = lane & 15;
  const int bm = blockIdx.y, bn = blockIdx.x;
  const int wm = w >> 1, wn = w & 1;
  f32x4 acc[4][4] = {};
  const char* Ab = (const char*)(A + (size_t)bm * 128 * K);
  const char* Bb = (const char*)(Bt + (size_t)bn * 128 * K);
  const int c0 = tid, c1 = tid + 256;
  const int rA0 = c0 >> 2, cb0 = (c0 & 3) * 16;
  const int rA1 = c1 >> 2, cb1 = (c1 & 3) * 16;

  for (int kt = 0; kt < K; kt += 32) {
    gload_lds16(Ab + (size_t)rA0 * K * 2 + kt * 2 + cb0, (char*)Al + c0 * 16);
    gload_lds16(Ab + (size_t)rA1 * K * 2 + kt * 2 + cb1, (char*)Al + c1 * 16);
    gload_lds16(Bb + (size_t)rA0 * K * 2 + kt * 2 + cb0, (char*)Bl + c0 * 16);
    gload_lds16(Bb + (size_t)rA1 * K * 2 + kt * 2 + cb1, (char*)Bl + c1 * 16);
    __syncthreads();
    short8 af[4], bf[4];
    #pragma unroll
    for (int mi = 0; mi < 4; mi++)
      af[mi] = *(const short8*)(Al + (wm * 64 + mi * 16 + lr) * 32 + grp * 8);
    #pragma unroll
    for (int nj = 0; nj < 4; nj++)
      bf[nj] = *(const short8*)(Bl + (wn * 64 + nj * 16 + lr) * 32 + grp * 8);
    #pragma unroll
    for (int mi = 0; mi < 4; mi++)
      #pragma unroll
      for (int nj = 0; nj < 4; nj++)
        acc[mi][nj] = MFMA_BF16(af[mi], bf[nj], acc[mi][nj]);
    __syncthreads();
  }

  const int rowBase = bm * 128 + wm * 64 + grp * 4;
  const int colBase = bn * 128 + wn * 64 + lr;
  #pragma unroll
  for (int mi = 0; mi < 4; mi++)
    #pragma unroll
    for (int nj = 0; nj < 4; nj++)
      #pragma unroll
      for (int r = 0; r < 4; r++)
        Co[(size_t)(rowBase + mi * 16 + r) * 2048 + colBase + nj * 16] = acc[mi][nj][r];
}

// ---------- flash attention v3: paired q-tiles (causal load balance) ----------
// grid (8 qpairs, 32 bh), 512 thr = 8 waves. Block i handles q-tiles i and
// 15-i (128 rows each): compute per block = 34 tile-steps, constant.
// K/V staged ONCE per pair. Counted vmcnt(4) keeps next tile's loads in
// flight across barriers (T4). Defer-max (T13) skips O-rescale when
// __all(tmax <= m_run + 8/ce).
__global__ __launch_bounds__(512, 2)
void attn_kernel(const u16* __restrict__ Q, const u16* __restrict__ K,
                 const u16* __restrict__ Vt, u16* __restrict__ ctx) {
  __shared__ u16 Kl[2][64 * 128];   // 16 KB each
  __shared__ u16 Vl[2][128 * 64];   // 16 KB each
  const int qtA = blockIdx.x, qtB = 15 - qtA;
  const int bh = blockIdx.y;
  const int b = bh >> 4, h = bh & 15;
  const int tid = threadIdx.x;
  const int w = tid >> 6, lane = tid & 63;
  const int grp = lane >> 4, lr = lane & 15;
  const int q0A = qtA * 128 + w * 16, qrowA = q0A + lr;
  const int q0B = qtB * 128 + w * 16, qrowB = q0B + lr;

  short8 qfA[4], qfB[4];
  {
    const u16* QpA = Q + ((size_t)(b * 2048 + qrowA)) * 2048 + h * 128;
    const u16* QpB = Q + ((size_t)(b * 2048 + qrowB)) * 2048 + h * 128;
    #pragma unroll
    for (int kk = 0; kk < 4; kk++) {
      qfA[kk] = *(const short8*)(QpA + kk * 32 + grp * 8);
      qfB[kk] = *(const short8*)(QpB + kk * 32 + grp * 8);
    }
  }

  f32x4 accA[8] = {}, accB[8] = {};
  float mA = -3.0e38f, lA = 0.0f, mB = -3.0e38f, lB = 0.0f;
  const float ce = 0.08838834764831845f * 1.4426950408889634f; // 1/sqrt(128)*log2(e)
  const float THR = 8.0f / ce;                                  // defer-max threshold

  const char* Kbh = (const char*)K  + ((size_t)b * 2048 * 2048 + h * 128) * 2;
  const char* Vbh = (const char*)Vt + ((size_t)(b * 2048 + h * 128)) * 2048 * 2;

  auto stage = [&](int buf, int kvt) {
    const int kv0 = kvt * 64;
    #pragma unroll
    for (int u = 0; u < 2; u++) {                  // K: 1024 x 16B chunks
      int c = tid + u * 512;
      int row = c >> 4, slot = c & 15;
      gload_lds16(Kbh + (size_t)(kv0 + row) * 4096 + ((slot ^ (row & 7)) << 4),
                  (char*)Kl[buf] + c * 16);
    }
    #pragma unroll
    for (int u = 0; u < 2; u++) {                  // V: 1024 x 16B chunks
      int c = tid + u * 512;
      int dd = c >> 3, slot = c & 7;
      gload_lds16(Vbh + (size_t)dd * 4096 + kv0 * 2 + ((slot ^ (dd & 7)) << 4),
                  (char*)Vl[buf] + c * 16);
    }
  };

  // one q-set's full tile update (QK^T -> online softmax -> PV)
  auto process = [&](const short8* qf, f32x4* acc, float& m_run, float& l_run,
                     int qrow, const char* Kc, const char* Vc, int kv0) {
    f32x4 sa[4] = {};
    #pragma unroll
    for (int kk = 0; kk < 4; kk++) {
      #pragma unroll
      for (int mi = 0; mi < 4; mi++) {
        const int krow = mi * 16 + lr;
        short8 kf = *(const short8*)(Kc + krow * 256 + (((kk * 4 + grp) ^ (krow & 7)) << 4));
        sa[mi] = MFMA_BF16(kf, qf[kk], sa[mi]);
      }
    }
    float tmax = -3.0e38f;
    const bool dg = (kv0 + 63 > qrow);
    #pragma unroll
    for (int mi = 0; mi < 4; mi++)
      #pragma unroll
      for (int r = 0; r < 4; r++) {
        float s = sa[mi][r];
        if (dg && (kv0 + mi * 16 + grp * 4 + r > qrow)) s = -3.0e38f;
        sa[mi][r] = s;
        tmax = fmaxf(tmax, s);
      }
    tmax = fmaxf(tmax, __shfl_xor(tmax, 16, 64));
    tmax = fmaxf(tmax, __shfl_xor(tmax, 32, 64));
    // defer-max: rescale only when some lane's tile-max exceeds m_run+THR
    if (!__all(tmax <= m_run + THR)) {
      const float m_new = fmaxf(m_run, tmax);
      const float alpha = exp2f((m_run - m_new) * ce);
      #pragma unroll
      for (int mi = 0; mi < 8; mi++) acc[mi] *= alpha;
      l_run *= alpha;
      m_run = m_new;
    }
    float psum = 0.0f;
    #pragma unroll
    for (int mi = 0; mi < 4; mi++)
      #pragma unroll
      for (int r = 0; r < 4; r++) {
        float e = exp2f((sa[mi][r] - m_run) * ce);
        sa[mi][r] = e;
        psum += e;
      }
    psum += __shfl_xor(psum, 16, 64);
    psum += __shfl_xor(psum, 32, 64);
    l_run += psum;

    short8 pb[2];
    #pragma unroll
    for (int kb = 0; kb < 2; kb++)
      #pragma unroll
      for (int i = 0; i < 4; i++) {
        pb[kb][i]     = (short)f2bf(sa[2 * kb][i]);
        pb[kb][4 + i] = (short)f2bf(sa[2 * kb + 1][i]);
      }
    #pragma unroll
    for (int mi = 0; mi < 8; mi++) {
      const int vrow = mi * 16 + lr;
      #pragma unroll
      for (int kb = 0; kb < 2; kb++) {
        short8 vf = *(const short8*)(Vc + vrow * 128 + (((kb * 4 + grp) ^ (vrow & 7)) << 4));
        acc[mi] = MFMA_BF16(vf, pb[kb], acc[mi]);
      }
    }
  };

  const int ntiles = 2 * qtB + 2;                  // B's causal range covers A's
  stage(0, 0);

  #pragma unroll 1
  for (int kvt = 0; kvt < ntiles; kvt++) {
    const int kv0 = kvt * 64;
    const int cur = kvt & 1;
    if (kvt + 1 < ntiles) {
      stage(cur ^ 1, kvt + 1);
      SB; asm volatile("s_waitcnt vmcnt(4)" ::: "memory"); SB;   // wait tile kvt only
    } else {
      SB; asm volatile("s_waitcnt vmcnt(0)" ::: "memory"); SB;
    }
    __builtin_amdgcn_s_barrier(); SB;              // buf[cur] landed everywhere

    const char* Kc = (const char*)Kl[cur];
    const char* Vc = (const char*)Vl[cur];
    if (kv0 <= q0B + 15)
      process(qfB, accB, mB, lB, qrowB, Kc, Vc, kv0);
    if (kv0 <= q0A + 15)
      process(qfA, accA, mA, lA, qrowA, Kc, Vc, kv0);

    SB; __builtin_amdgcn_s_barrier(); SB;          // all done reading buf[cur]
  }

  const float invA = 1.0f / lA, invB = 1.0f / lB;
  u16* CpA = ctx + ((size_t)(b * 2048 + qrowA)) * 2048 + h * 128;
  u16* CpB = ctx + ((size_t)(b * 2048 + qrowB)) * 2048 + h * 128;
  #pragma unroll
  for (int mi = 0; mi < 8; mi++) {
    ushort4 oa, ob;
    oa.x = f2bf(accA[mi][0] * invA); oa.y = f2bf(accA[mi][1] * invA);
    oa.z = f2bf(accA[mi][2] * invA); oa.w = f2bf(accA[mi][3] * invA);
    ob.x = f2bf(accB[mi][0] * invB); ob.y = f2bf(accB[mi][1] * invB);
    ob.z = f2bf(accB[mi][2] * invB); ob.w = f2bf(accB[mi][3] * invB);
    *(ushort4*)(CpA + mi * 16 + grp * 4) = oa;
    *(ushort4*)(CpB + mi * 16 + grp * 4) = ob;
  }
}

// ---------- launch ----------
extern "C" void kernel_launch(void* const* d_in, const int* in_sizes, int n_in,
                              void* d_out, int out_size, void* d_ws, size_t ws_size,
                              hipStream_t stream) {
  const float* x  = (const float*)d_in[0];
  const float* Wq = (const float*)d_in[1];
  const float* Wk = (const float*)d_in[2];
  const float* Wv = (const float*)d_in[3];
  const float* Wo = (const float*)d_in[4];
  float* out = (float*)d_out;
  char* ws = (char*)d_ws;
  if (ws_size < WS_NEED) return;

  u16* xb    = (u16*)(ws + OFF_XB);
  u16* Wqkvt = (u16*)(ws + OFF_WQKVT);
  u16* Wot   = (u16*)(ws + OFF_WOT);
  u16* Qb    = (u16*)(ws + OFF_Q);
  u16* Kb    = (u16*)(ws + OFF_K);
  u16* Vtb   = (u16*)(ws + OFF_VT);
  u16* ctxb  = (u16*)(ws + OFF_CTX);
  float* ctab = (float*)(ws + OFF_COS);
  float* stab = (float*)(ws + OFF_SIN);

  cast_x_kernel<<<8192, 256, 0, stream>>>(x, xb, 2097152);
  castT_w_kernel<<<dim3(64, 64, 4), dim3(32, 8), 0, stream>>>(Wq, Wk, Wv, Wo, Wqkvt, Wot);
  rope_table_kernel<<<512, 256, 0, stream>>>(ctab, stab);
  gemm8_qkv_kernel<<<dim3(24, 16), 512, 0, stream>>>(xb, Wqkvt, Qb, Kb, Vtb);
  rope_apply_kernel<<<dim3(16384, 2), 256, 0, stream>>>(Qb, Kb, ctab, stab);
  attn_kernel<<<dim3(8, 32), 512, 0, stream>>>(Qb, Kb, Vtb, ctxb);
  gemm_bt_kernel<<<dim3(16, 32), 256, 0, stream>>>(ctxb, Wot, out, 2048);
}

// Round 12
// 415.589 us; speedup vs baseline: 2.8666x; 1.0112x over previous
//
#include <hip/hip_runtime.h>
#include <hip/hip_bf16.h>

// ---------- types ----------
typedef __attribute__((ext_vector_type(8))) __bf16 bf16x8;
typedef __attribute__((ext_vector_type(8))) short  short8;
typedef __attribute__((ext_vector_type(4))) float  f32x4;
typedef unsigned short u16;
typedef unsigned int   u32;

__device__ __forceinline__ u16 f2bf(float f) {
  u32 u = __builtin_bit_cast(u32, f);
  u += 0x7fffu + ((u >> 16) & 1u);          // round-to-nearest-even
  return (u16)(u >> 16);
}
__device__ __forceinline__ float bf2f(u16 h) {
  return __builtin_bit_cast(float, (u32)h << 16);
}

#define MFMA_BF16(a, b, c) __builtin_amdgcn_mfma_f32_16x16x32_bf16( \
    __builtin_bit_cast(bf16x8, (a)), __builtin_bit_cast(bf16x8, (b)), (c), 0, 0, 0)

__device__ __forceinline__ void gload_lds16(const void* g, void* l) {
  __builtin_amdgcn_global_load_lds(
      (const __attribute__((address_space(1))) void*)g,
      (__attribute__((address_space(3))) void*)l, 16, 0, 0);
}

// ---------- problem constants ----------
#define SEQ   2048
#define DMODEL 2048
#define NH    16
#define HD    128

// ---------- workspace layout (bytes) ----------
static constexpr size_t SZ_MAT   = 4096ull * 2048 * 2;        // (b*s, d) bf16 = 16 MiB
static constexpr size_t OFF_XB   = 0;
static constexpr size_t OFF_WQKVT= OFF_XB   + SZ_MAT;          // Wq^T|Wk^T|Wv^T
static constexpr size_t OFF_WOT  = OFF_WQKVT+ 3ull*2048*2048*2;
static constexpr size_t OFF_Q    = OFF_WOT  + 2048ull*2048*2;
static constexpr size_t OFF_K    = OFF_Q    + SZ_MAT;
static constexpr size_t OFF_VT   = OFF_K    + SZ_MAT;          // Vp[b*2048+h*128+dd][s_perm]
static constexpr size_t OFF_CTX  = OFF_VT   + SZ_MAT;
static constexpr size_t OFF_COS  = OFF_CTX  + SZ_MAT;
static constexpr size_t OFF_SIN  = OFF_COS  + 2048ull*64*4;
static constexpr size_t WS_NEED  = OFF_SIN  + 2048ull*64*4;    // ~113 MiB

// ---------- prep kernels ----------
__global__ void cast_x_kernel(const float* __restrict__ x, u16* __restrict__ xb, int n4) {
  int id = blockIdx.x * blockDim.x + threadIdx.x;
  if (id >= n4) return;
  float4 v = ((const float4*)x)[id];
  ushort4 o;
  o.x = f2bf(v.x); o.y = f2bf(v.y); o.z = f2bf(v.z); o.w = f2bf(v.w);
  ((ushort4*)xb)[id] = o;
}

__global__ void castT_w_kernel(const float* __restrict__ W0, const float* __restrict__ W1,
                               const float* __restrict__ W2, const float* __restrict__ W3,
                               u16* __restrict__ Wqkvt, u16* __restrict__ Wot) {
  __shared__ float tile[32][33];
  int z = blockIdx.z;
  const float* W = (z == 0) ? W0 : (z == 1) ? W1 : (z == 2) ? W2 : W3;
  u16* Out = (z < 3) ? (Wqkvt + (size_t)z * 2048 * 2048) : Wot;
  int n0 = blockIdx.x * 32, k0 = blockIdx.y * 32;
  int tx = threadIdx.x, ty = threadIdx.y;   // (32,8)
  #pragma unroll
  for (int i = 0; i < 4; i++)
    tile[ty + 8 * i][tx] = W[(size_t)(k0 + ty + 8 * i) * 2048 + n0 + tx];
  __syncthreads();
  #pragma unroll
  for (int i = 0; i < 4; i++)
    Out[(size_t)(n0 + ty + 8 * i) * 2048 + k0 + tx] = f2bf(tile[tx][ty + 8 * i]);
}

__global__ void rope_table_kernel(float* __restrict__ ct, float* __restrict__ st) {
  int id = blockIdx.x * blockDim.x + threadIdx.x;  // 2048*64
  int pos = id >> 6, j = id & 63;
  float inv = exp2f(-(float)j * (13.287712379549449f / 64.0f));
  float a = (float)pos * inv;
  ct[id] = cosf(a);
  st[id] = sinf(a);
}

__global__ void rope_apply_kernel(u16* __restrict__ Q, u16* __restrict__ K,
                                  const float* __restrict__ ct, const float* __restrict__ st) {
  int id = blockIdx.x * blockDim.x + threadIdx.x;    // < 4096*16*64
  u16* P = blockIdx.y ? K : Q;
  int row = id >> 10;
  int r = id & 1023;
  int hh = r >> 6, j = r & 63;
  int pos = row & 2047;
  size_t base = (size_t)row * 2048 + hh * 128 + j;
  float x1 = bf2f(P[base]), x2 = bf2f(P[base + 64]);
  float c = ct[pos * 64 + j], s = st[pos * 64 + j];
  P[base]      = f2bf(x1 * c - x2 * s);
  P[base + 64] = f2bf(x2 * c + x1 * s);
}

// ======================================================================
// 256x128 8-phase GEMM (T2+T3+T4+T5): C[4096 x 6144] = A @ Bt^T, K=2048.
// Grid 48x16 = 768 blocks = EXACTLY 3 full rounds of 256 CUs.
// 8 waves (4M x 2N), per-wave 64x64, BK=64, 96 KiB LDS double-buffer.
// B fragments MUST persist across phases: bfr[4][2] indexed by NG+nj
// (P4/P8's MMQ2(.,0) consume the NG0-1 fragments loaded 3 phases earlier;
// R10's bfr[nj] reuse clobbered them -> absmax 1.15 regression).
// vmcnt ledger (loads/iter: P1:2 P2:2 P3:1 P4:2 P5:2 P6:1 P7:1 P8:1):
//   P4 waits vmcnt(3) -> retires K1.A + prev B1 before P5 reads A1/B1.
//   P8 waits vmcnt(2) -> retires all K2 stages before next-iter reads A0/B0.
//   Steady-state invariant at iter entry: 2 outstanding (next-odd-K B1).
// ======================================================================
#define SB __builtin_amdgcn_sched_barrier(0)
#define BAR()   do { SB; __builtin_amdgcn_s_barrier(); SB; } while (0)
#define VMCNT3() do { SB; asm volatile("s_waitcnt vmcnt(3)" ::: "memory"); SB; } while (0)
#define VMCNT2() do { SB; asm volatile("s_waitcnt vmcnt(2)" ::: "memory"); SB; } while (0)
#define VMCNT0() do { SB; asm volatile("s_waitcnt vmcnt(0)" ::: "memory"); SB; } while (0)

// A operand: [256 rows][8 slots of 16B]; half H = 128 rows = 2 loads/thread.
#define STAGE_A(gb, kt, H, lb)                                                 \
  do { _Pragma("unroll")                                                       \
    for (int u = 0; u < 2; u++) {                                              \
      int c = tid + u * 512;                                                   \
      int rr = c >> 3, sl = c & 7;                                             \
      gload_lds16((gb) + (size_t)((H) * 128 + rr) * 4096 + (size_t)(kt) * 128  \
                       + ((sl ^ (rr & 7)) << 4),                               \
                  (lb) + (H) * 16384 + c * 16);                                \
    } } while (0)

// B operand: [128 rows][8 slots]; half H = 64 rows = 1 load/thread.
#define STAGE_B(gb, kt, H, lb)                                                 \
  do { int c = tid;                                                            \
    int rr = c >> 3, sl = c & 7;                                               \
    gload_lds16((gb) + (size_t)((H) * 64 + rr) * 4096 + (size_t)(kt) * 128     \
                     + ((sl ^ (rr & 7)) << 4),                                 \
                (lb) + (H) * 8192 + c * 16);                                   \
  } while (0)

#define LDA2(lb, MG)                                                           \
  do { _Pragma("unroll")                                                       \
    for (int mi = 0; mi < 2; mi++) {                                           \
      af[mi][0] = *(const short8*)((lb) + aoff + ((MG) + mi) * 2048 + sw0);    \
      af[mi][1] = *(const short8*)((lb) + aoff + ((MG) + mi) * 2048 + sw1);    \
    } } while (0)

#define LDB2(lb, NG)                                                           \
  do { _Pragma("unroll")                                                       \
    for (int nj = 0; nj < 2; nj++) {                                           \
      bfr[(NG) + nj][0] = *(const short8*)((lb) + boff + ((NG) + nj) * 2048 + sw0); \
      bfr[(NG) + nj][1] = *(const short8*)((lb) + boff + ((NG) + nj) * 2048 + sw1); \
    } } while (0)

#define MMQ2(MG, NG)                                                           \
  do {                                                                         \
    __builtin_amdgcn_s_setprio(1);                                             \
    _Pragma("unroll")                                                          \
    for (int mi = 0; mi < 2; mi++) {                                           \
      _Pragma("unroll")                                                        \
      for (int nj = 0; nj < 2; nj++) {                                         \
        acc[(MG) + mi][(NG) + nj] =                                            \
            MFMA_BF16(af[mi][0], bfr[(NG) + nj][0], acc[(MG) + mi][(NG) + nj]);\
        acc[(MG) + mi][(NG) + nj] =                                            \
            MFMA_BF16(af[mi][1], bfr[(NG) + nj][1], acc[(MG) + mi][(NG) + nj]);\
      }                                                                        \
    }                                                                          \
    __builtin_amdgcn_s_setprio(0);                                             \
  } while (0)

// Computes K-tiles (K1v-1) from A0/B0 and K1v from A1/B1.
// Stages: K1.A -> A1 (P1,P2); K2.B -> B0 (P3,P6); K2.A -> A0 (P4,P5);
//         K3.B -> B1 (P7,P8). Each stage after its region's last reader.
#define GEMM8_ITER(K1v, K2v, K3v, LAST)                                        \
  do {                                                                         \
    LDA2(A0p, 0); LDB2(B0p, 0);                                                \
    STAGE_A(Ab, (K1v), 0, A1p);                                                \
    BAR(); MMQ2(0, 0); BAR();                                                  \
    LDB2(B0p, 2);                                                              \
    STAGE_A(Ab, (K1v), 1, A1p);                                                \
    BAR(); MMQ2(0, 2); BAR();                                                  \
    LDA2(A0p, 2);                                                              \
    if (!(LAST)) STAGE_B(Bb, (K2v), 0, B0p);                                   \
    BAR(); MMQ2(2, 2); BAR();                                                  \
    if (!(LAST)) STAGE_A(Ab, (K2v), 0, A0p);                                   \
    if (LAST) { VMCNT0(); } else { VMCNT3(); }                                 \
    BAR(); MMQ2(2, 0); BAR();                                                  \
    LDA2(A1p, 0); LDB2(B1p, 0);                                                \
    if (!(LAST)) STAGE_A(Ab, (K2v), 1, A0p);                                   \
    BAR(); MMQ2(0, 0); BAR();                                                  \
    LDB2(B1p, 2);                                                              \
    if (!(LAST)) STAGE_B(Bb, (K2v), 1, B0p);                                   \
    BAR(); MMQ2(0, 2); BAR();                                                  \
    LDA2(A1p, 2);                                                              \
    if (!(LAST)) STAGE_B(Bb, (K3v), 0, B1p);                                   \
    BAR(); MMQ2(2, 2); BAR();                                                  \
    if (!(LAST)) { STAGE_B(Bb, (K3v), 1, B1p); VMCNT2(); }                     \
    BAR(); MMQ2(2, 0); BAR();                                                  \
  } while (0)

__global__ __launch_bounds__(512, 2)
void gemm8_qkv_kernel(const u16* __restrict__ A, const u16* __restrict__ Bt,
                      u16* __restrict__ Qo, u16* __restrict__ Ko,
                      u16* __restrict__ Vto) {
  __shared__ u16 Asm[2][16384];   // [buf][256r][64c] 32 KB each
  __shared__ u16 Bsm[2][8192];    // [buf][128r][64c] 16 KB each
  const int tid = threadIdx.x;
  const int lane = tid & 63, w = tid >> 6;
  const int grp = lane >> 4, lr = lane & 15;
  const int wm = w >> 1, wn = w & 1;          // 4 x 2 waves, 64x64 each
  const int bm = blockIdx.y, bn = blockIdx.x; // 16 x 48

  const char* Ab = (const char*)A + (size_t)bm * 256 * 4096;
  const char* Bb = (const char*)Bt + (size_t)bn * 128 * 4096;
  char* A0p = (char*)Asm[0]; char* A1p = (char*)Asm[1];
  char* B0p = (char*)Bsm[0]; char* B1p = (char*)Bsm[1];

  f32x4 acc[4][4] = {};
  short8 af[2][2], bfr[4][2];
  const int aoff = wm * 8192 + lr * 128;      // wave m-origin (64 rows) + lr
  const int boff = wn * 8192 + lr * 128;      // wave n-origin (64 rows) + lr
  const int sw0 = ((grp    ) ^ (lr & 7)) << 4;
  const int sw1 = ((grp + 4) ^ (lr & 7)) << 4;

  // prologue: k0 A+B fully, k1 B; wait k0 (6 oldest of 8)
  STAGE_A(Ab, 0, 0, A0p);
  STAGE_A(Ab, 0, 1, A0p);
  STAGE_B(Bb, 0, 0, B0p);
  STAGE_B(Bb, 0, 1, B0p);
  STAGE_B(Bb, 1, 0, B1p);
  STAGE_B(Bb, 1, 1, B1p);
  VMCNT2();
  BAR();

  #pragma unroll 1
  for (int t = 0; t < 15; ++t) {
    GEMM8_ITER(2 * t + 1, 2 * t + 2, 2 * t + 3, false);
  }
  GEMM8_ITER(31, 0, 0, true);

  // epilogue: C/D layout col = lane&15, row = 4*(lane>>4)+reg
  const int seg = bn >> 4;                    // 0=Q 1=K 2=V (16 bn per segment)
  const int row0 = bm * 256 + wm * 64 + grp * 4;
  const int col0 = (bn & 15) * 128 + wn * 64 + lr;
  if (seg < 2) {
    u16* O = seg ? Ko : Qo;
    #pragma unroll
    for (int ai = 0; ai < 4; ai++)
      #pragma unroll
      for (int nj = 0; nj < 4; nj++) {
        int col = col0 + nj * 16;
        int row = row0 + ai * 16;
        #pragma unroll
        for (int r = 0; r < 4; r++)
          O[(size_t)(row + r) * 2048 + col] = f2bf(acc[ai][nj][r]);
      }
  } else {
    // V: write Vp[(b*2048 + h*128+dd)][s_perm]; 4 regs = 4 consecutive s.
    #pragma unroll
    for (int ai = 0; ai < 4; ai++) {
      int row = row0 + ai * 16;               // = b*2048 + s (s multiple of 4)
      int b = row >> 11, s = row & 2047;
      int sp = (s & ~31) | (((s >> 2) & 3) << 3) | (((s >> 4) & 1) << 2);
      #pragma unroll
      for (int nj = 0; nj < 4; nj++) {
        int colv = col0 + nj * 16;            // h*128 + dd
        ushort4 o;
        o.x = f2bf(acc[ai][nj][0]); o.y = f2bf(acc[ai][nj][1]);
        o.z = f2bf(acc[ai][nj][2]); o.w = f2bf(acc[ai][nj][3]);
        *(ushort4*)(Vto + (size_t)(b * 2048 + colv) * 2048 + sp) = o;
      }
    }
  }
}

// ---------- out-proj GEMM: 128x128 tile, 4 waves ----------
__global__ __launch_bounds__(256)
void gemm_bt_kernel(const u16* __restrict__ A, const u16* __restrict__ Bt,
                    float* __restrict__ Co, int K) {
  __shared__ u16 Al[128 * 32];
  __shared__ u16 Bl[128 * 32];
  const int tid = threadIdx.x;
  const int lane = tid & 63;
  const int w = tid >> 6;
  const int grp = lane >> 4, lr = lane & 15;
  const int bm = blockIdx.y, bn = blockIdx.x;
  const int wm = w >> 1, wn = w & 1;
  f32x4 acc[4][4] = {};
  const char* Ab = (const char*)(A + (size_t)bm * 128 * K);
  const char* Bb = (const char*)(Bt + (size_t)bn * 128 * K);
  const int c0 = tid, c1 = tid + 256;
  const int rA0 = c0 >> 2, cb0 = (c0 & 3) * 16;
  const int rA1 = c1 >> 2, cb1 = (c1 & 3) * 16;

  for (int kt = 0; kt < K; kt += 32) {
    gload_lds16(Ab + (size_t)rA0 * K * 2 + kt * 2 + cb0, (char*)Al + c0 * 16);
    gload_lds16(Ab + (size_t)rA1 * K * 2 + kt * 2 + cb1, (char*)Al + c1 * 16);
    gload_lds16(Bb + (size_t)rA0 * K * 2 + kt * 2 + cb0, (char*)Bl + c0 * 16);
    gload_lds16(Bb + (size_t)rA1 * K * 2 + kt * 2 + cb1, (char*)Bl + c1 * 16);
    __syncthreads();
    short8 af[4], bf[4];
    #pragma unroll
    for (int mi = 0; mi < 4; mi++)
      af[mi] = *(const short8*)(Al + (wm * 64 + mi * 16 + lr) * 32 + grp * 8);
    #pragma unroll
    for (int nj = 0; nj < 4; nj++)
      bf[nj] = *(const short8*)(Bl + (wn * 64 + nj * 16 + lr) * 32 + grp * 8);
    #pragma unroll
    for (int mi = 0; mi < 4; mi++)
      #pragma unroll
      for (int nj = 0; nj < 4; nj++)
        acc[mi][nj] = MFMA_BF16(af[mi], bf[nj], acc[mi][nj]);
    __syncthreads();
  }

  const int rowBase = bm * 128 + wm * 64 + grp * 4;
  const int colBase = bn * 128 + wn * 64 + lr;
  #pragma unroll
  for (int mi = 0; mi < 4; mi++)
    #pragma unroll
    for (int nj = 0; nj < 4; nj++)
      #pragma unroll
      for (int r = 0; r < 4; r++)
        Co[(size_t)(rowBase + mi * 16 + r) * 2048 + colBase + nj * 16] = acc[mi][nj][r];
}

// ---------- flash attention v3: paired q-tiles (causal load balance) ----------
__global__ __launch_bounds__(512, 2)
void attn_kernel(const u16* __restrict__ Q, const u16* __restrict__ K,
                 const u16* __restrict__ Vt, u16* __restrict__ ctx) {
  __shared__ u16 Kl[2][64 * 128];   // 16 KB each
  __shared__ u16 Vl[2][128 * 64];   // 16 KB each
  const int qtA = blockIdx.x, qtB = 15 - qtA;
  const int bh = blockIdx.y;
  const int b = bh >> 4, h = bh & 15;
  const int tid = threadIdx.x;
  const int w = tid >> 6, lane = tid & 63;
  const int grp = lane >> 4, lr = lane & 15;
  const int q0A = qtA * 128 + w * 16, qrowA = q0A + lr;
  const int q0B = qtB * 128 + w * 16, qrowB = q0B + lr;

  short8 qfA[4], qfB[4];
  {
    const u16* QpA = Q + ((size_t)(b * 2048 + qrowA)) * 2048 + h * 128;
    const u16* QpB = Q + ((size_t)(b * 2048 + qrowB)) * 2048 + h * 128;
    #pragma unroll
    for (int kk = 0; kk < 4; kk++) {
      qfA[kk] = *(const short8*)(QpA + kk * 32 + grp * 8);
      qfB[kk] = *(const short8*)(QpB + kk * 32 + grp * 8);
    }
  }

  f32x4 accA[8] = {}, accB[8] = {};
  float mA = -3.0e38f, lA = 0.0f, mB = -3.0e38f, lB = 0.0f;
  const float ce = 0.08838834764831845f * 1.4426950408889634f; // 1/sqrt(128)*log2(e)
  const float THR = 8.0f / ce;                                  // defer-max threshold

  const char* Kbh = (const char*)K  + ((size_t)b * 2048 * 2048 + h * 128) * 2;
  const char* Vbh = (const char*)Vt + ((size_t)(b * 2048 + h * 128)) * 2048 * 2;

  auto stage = [&](int buf, int kvt) {
    const int kv0 = kvt * 64;
    #pragma unroll
    for (int u = 0; u < 2; u++) {                  // K: 1024 x 16B chunks
      int c = tid + u * 512;
      int row = c >> 4, slot = c & 15;
      gload_lds16(Kbh + (size_t)(kv0 + row) * 4096 + ((slot ^ (row & 7)) << 4),
                  (char*)Kl[buf] + c * 16);
    }
    #pragma unroll
    for (int u = 0; u < 2; u++) {                  // V: 1024 x 16B chunks
      int c = tid + u * 512;
      int dd = c >> 3, slot = c & 7;
      gload_lds16(Vbh + (size_t)dd * 4096 + kv0 * 2 + ((slot ^ (dd & 7)) << 4),
                  (char*)Vl[buf] + c * 16);
    }
  };

  // one q-set's full tile update (QK^T -> online softmax -> PV)
  auto process = [&](const short8* qf, f32x4* acc, float& m_run, float& l_run,
                     int qrow, const char* Kc, const char* Vc, int kv0) {
    f32x4 sa[4] = {};
    #pragma unroll
    for (int kk = 0; kk < 4; kk++) {
      #pragma unroll
      for (int mi = 0; mi < 4; mi++) {
        const int krow = mi * 16 + lr;
        short8 kf = *(const short8*)(Kc + krow * 256 + (((kk * 4 + grp) ^ (krow & 7)) << 4));
        sa[mi] = MFMA_BF16(kf, qf[kk], sa[mi]);
      }
    }
    float tmax = -3.0e38f;
    const bool dg = (kv0 + 63 > qrow);
    #pragma unroll
    for (int mi = 0; mi < 4; mi++)
      #pragma unroll
      for (int r = 0; r < 4; r++) {
        float s = sa[mi][r];
        if (dg && (kv0 + mi * 16 + grp * 4 + r > qrow)) s = -3.0e38f;
        sa[mi][r] = s;
        tmax = fmaxf(tmax, s);
      }
    tmax = fmaxf(tmax, __shfl_xor(tmax, 16, 64));
    tmax = fmaxf(tmax, __shfl_xor(tmax, 32, 64));
    // defer-max: rescale only when some lane's tile-max exceeds m_run+THR
    if (!__all(tmax <= m_run + THR)) {
      const float m_new = fmaxf(m_run, tmax);
      const float alpha = exp2f((m_run - m_new) * ce);
      #pragma unroll
      for (int mi = 0; mi < 8; mi++) acc[mi] *= alpha;
      l_run *= alpha;
      m_run = m_new;
    }
    float psum = 0.0f;
    #pragma unroll
    for (int mi = 0; mi < 4; mi++)
      #pragma unroll
      for (int r = 0; r < 4; r++) {
        float e = exp2f((sa[mi][r] - m_run) * ce);
        sa[mi][r] = e;
        psum += e;
      }
    psum += __shfl_xor(psum, 16, 64);
    psum += __shfl_xor(psum, 32, 64);
    l_run += psum;

    short8 pb[2];
    #pragma unroll
    for (int kb = 0; kb < 2; kb++)
      #pragma unroll
      for (int i = 0; i < 4; i++) {
        pb[kb][i]     = (short)f2bf(sa[2 * kb][i]);
        pb[kb][4 + i] = (short)f2bf(sa[2 * kb + 1][i]);
      }
    #pragma unroll
    for (int mi = 0; mi < 8; mi++) {
      const int vrow = mi * 16 + lr;
      #pragma unroll
      for (int kb = 0; kb < 2; kb++) {
        short8 vf = *(const short8*)(Vc + vrow * 128 + (((kb * 4 + grp) ^ (vrow & 7)) << 4));
        acc[mi] = MFMA_BF16(vf, pb[kb], acc[mi]);
      }
    }
  };

  const int ntiles = 2 * qtB + 2;                  // B's causal range covers A's
  stage(0, 0);

  #pragma unroll 1
  for (int kvt = 0; kvt < ntiles; kvt++) {
    const int kv0 = kvt * 64;
    const int cur = kvt & 1;
    if (kvt + 1 < ntiles) {
      stage(cur ^ 1, kvt + 1);
      SB; asm volatile("s_waitcnt vmcnt(4)" ::: "memory"); SB;   // wait tile kvt only
    } else {
      SB; asm volatile("s_waitcnt vmcnt(0)" ::: "memory"); SB;
    }
    __builtin_amdgcn_s_barrier(); SB;              // buf[cur] landed everywhere

    const char* Kc = (const char*)Kl[cur];
    const char* Vc = (const char*)Vl[cur];
    if (kv0 <= q0B + 15)
      process(qfB, accB, mB, lB, qrowB, Kc, Vc, kv0);
    if (kv0 <= q0A + 15)
      process(qfA, accA, mA, lA, qrowA, Kc, Vc, kv0);

    SB; __builtin_amdgcn_s_barrier(); SB;          // all done reading buf[cur]
  }

  const float invA = 1.0f / lA, invB = 1.0f / lB;
  u16* CpA = ctx + ((size_t)(b * 2048 + qrowA)) * 2048 + h * 128;
  u16* CpB = ctx + ((size_t)(b * 2048 + qrowB)) * 2048 + h * 128;
  #pragma unroll
  for (int mi = 0; mi < 8; mi++) {
    ushort4 oa, ob;
    oa.x = f2bf(accA[mi][0] * invA); oa.y = f2bf(accA[mi][1] * invA);
    oa.z = f2bf(accA[mi][2] * invA); oa.w = f2bf(accA[mi][3] * invA);
    ob.x = f2bf(accB[mi][0] * invB); ob.y = f2bf(accB[mi][1] * invB);
    ob.z = f2bf(accB[mi][2] * invB); ob.w = f2bf(accB[mi][3] * invB);
    *(ushort4*)(CpA + mi * 16 + grp * 4) = oa;
    *(ushort4*)(CpB + mi * 16 + grp * 4) = ob;
  }
}

// ---------- launch ----------
extern "C" void kernel_launch(void* const* d_in, const int* in_sizes, int n_in,
                              void* d_out, int out_size, void* d_ws, size_t ws_size,
                              hipStream_t stream) {
  const float* x  = (const float*)d_in[0];
  const float* Wq = (const float*)d_in[1];
  const float* Wk = (const float*)d_in[2];
  const float* Wv = (const float*)d_in[3];
  const float* Wo = (const float*)d_in[4];
  float* out = (float*)d_out;
  char* ws = (char*)d_ws;
  if (ws_size < WS_NEED) return;

  u16* xb    = (u16*)(ws + OFF_XB);
  u16* Wqkvt = (u16*)(ws + OFF_WQKVT);
  u16* Wot   = (u16*)(ws + OFF_WOT);
  u16* Qb    = (u16*)(ws + OFF_Q);
  u16* Kb    = (u16*)(ws + OFF_K);
  u16* Vtb   = (u16*)(ws + OFF_VT);
  u16* ctxb  = (u16*)(ws + OFF_CTX);
  float* ctab = (float*)(ws + OFF_COS);
  float* stab = (float*)(ws + OFF_SIN);

  cast_x_kernel<<<8192, 256, 0, stream>>>(x, xb, 2097152);
  castT_w_kernel<<<dim3(64, 64, 4), dim3(32, 8), 0, stream>>>(Wq, Wk, Wv, Wo, Wqkvt, Wot);
  rope_table_kernel<<<512, 256, 0, stream>>>(ctab, stab);
  gemm8_qkv_kernel<<<dim3(48, 16), 512, 0, stream>>>(xb, Wqkvt, Qb, Kb, Vtb);
  rope_apply_kernel<<<dim3(16384, 2), 256, 0, stream>>>(Qb, Kb, ctab, stab);
  attn_kernel<<<dim3(8, 32), 512, 0, stream>>>(Qb, Kb, Vtb, ctxb);
  gemm_bt_kernel<<<dim3(16, 32), 256, 0, stream>>>(ctxb, Wot, out, 2048);
}